// Round 1
// baseline (202.892 us; speedup 1.0000x reference)
//
#include <hip/hip_runtime.h>

#define NN 384
#define HH 32
#define MM 50

// Closed-form cardinal cubic B-spline features for the efficient-kan uniform
// grid: GRID_SIZE=5, SPLINE_ORDER=3, h=0.4, knots g[c]=(c-3)*h-1, c=0..11.
// For x in cell c (g[c]<=x<g[c+1]), nonzero final bases are k=c-3..c with the
// standard uniform cubic polynomials in t=(x-g[c])/h. kb=(int)floor((x+1)/h)
// so that k=kb+r, r=0..3. Out-of-domain x -> all-zero basis (s=0) and kb
// pushed out of [0,8) so predicated gathers skip.
__device__ __forceinline__ void featEval(float x, float& sil, int& kb, float b[4]) {
  sil = x / (1.0f + __expf(-x));                  // silu
  const float u  = (x + 1.0f) * 2.5f;
  const float fu = floorf(u);
  const bool valid = (fu >= -3.0f) && (fu <= 7.0f);
  const float s = valid ? (1.0f / 6.0f) : 0.0f;
  kb = valid ? (int)fu : 100;
  const float tt = u - fu;
  const float t2 = tt * tt, t3 = t2 * tt, omt = 1.0f - tt;
  b[0] = omt * omt * omt * s;                     // k = c-3
  b[1] = (3.0f * t3 - 6.0f * t2 + 4.0f) * s;      // k = c-2
  b[2] = (-3.0f * t3 + 3.0f * t2 + 3.0f * tt + 1.0f) * s; // k = c-1
  b[3] = t3 * s;                                  // k = c
}

// Per-modality layer-1 decomposition: A[i][o] (first-half weight cols on row i)
// and Bt[o][j] (second-half cols on row j, stored transposed for coalesced
// stage-C reads). One block per row; 32 feature threads then 50+50 output threads.
__global__ __launch_bounds__(128) void kanAB_kernel(
    const float* __restrict__ q, const float* __restrict__ bw,
    const float* __restrict__ sw, float* __restrict__ A, float* __restrict__ Bt)
{
  __shared__ float s_sil[HH];
  __shared__ int   s_kb[HH];
  __shared__ float s_b[HH][4];
  const int tid = threadIdx.x;
  const int i = blockIdx.x;
  if (tid < HH) {
    float b[4]; float sil; int kb;
    featEval(q[i * HH + tid], sil, kb, b);
    s_sil[tid] = sil; s_kb[tid] = kb;
    s_b[tid][0] = b[0]; s_b[tid][1] = b[1]; s_b[tid][2] = b[2]; s_b[tid][3] = b[3];
  }
  __syncthreads();
  const int half = tid >> 6;      // 0 -> A (cols 0..31), 1 -> B (cols 32..63)
  const int o = tid & 63;
  if (o < MM) {
    const int colbase = half * HH;
    float acc = 0.0f;
    for (int d = 0; d < HH; ++d) {
      const int col = colbase + d;
      acc = fmaf(s_sil[d], bw[o * (2 * HH) + col], acc);
      const float* swrow = sw + ((size_t)(o * (2 * HH) + col) << 3);
      const int kb = s_kb[d];
#pragma unroll
      for (int r = 0; r < 4; ++r) {
        const int k = kb + r;
        if ((unsigned)k < 8u) acc = fmaf(s_b[d][r], swrow[k], acc);
      }
    }
    if (half == 0) A[i * MM + o] = acc;
    else           Bt[o * NN + i] = acc;
  }
}

// Dynamic modal fusion weights: feats = [mean(x), mean(y), mean(t)] (96),
// kan2 -> 3 logits -> softmax -> wout[3]. One tiny block.
__global__ __launch_bounds__(128) void fusion_kernel(
    const float* __restrict__ x, const float* __restrict__ y, const float* __restrict__ tg,
    const float* __restrict__ f1bw, const float* __restrict__ f1sw,
    const float* __restrict__ f2bw, const float* __restrict__ f2sw,
    float* __restrict__ wout)
{
  __shared__ float sil[96];
  __shared__ int   kb[96];
  __shared__ float bs[96][4];
  __shared__ float z1[MM];
  __shared__ float s3[3];
  const int tid = threadIdx.x;
  if (tid < 96) {
    const float* src = (tid < 32) ? x : ((tid < 64) ? y : tg);
    const int col = tid & 31;
    float acc = 0.0f;
    for (int r = 0; r < NN; ++r) acc += src[r * HH + col];
    const float fv = acc * (1.0f / NN);
    float b[4]; float s; int k;
    featEval(fv, s, k, b);
    sil[tid] = s; kb[tid] = k;
    bs[tid][0] = b[0]; bs[tid][1] = b[1]; bs[tid][2] = b[2]; bs[tid][3] = b[3];
  }
  __syncthreads();
  if (tid < MM) {
    float acc = 0.0f;
    for (int d = 0; d < 96; ++d) {
      acc = fmaf(sil[d], f1bw[tid * 96 + d], acc);
      const float* swrow = f1sw + ((size_t)(tid * 96 + d) << 3);
      const int kbd = kb[d];
#pragma unroll
      for (int r = 0; r < 4; ++r) {
        const int k = kbd + r;
        if ((unsigned)k < 8u) acc = fmaf(bs[d][r], swrow[k], acc);
      }
    }
    z1[tid] = acc;
  }
  __syncthreads();
  if (tid < MM) {
    float b[4]; float s; int k;
    featEval(z1[tid], s, k, b);
    sil[tid] = s; kb[tid] = k;
    bs[tid][0] = b[0]; bs[tid][1] = b[1]; bs[tid][2] = b[2]; bs[tid][3] = b[3];
  }
  __syncthreads();
  if (tid < 3) {
    float acc = 0.0f;
    for (int d = 0; d < MM; ++d) {
      acc = fmaf(sil[d], f2bw[tid * MM + d], acc);
      const float* swrow = f2sw + ((size_t)(tid * MM + d) << 3);
      const int kbd = kb[d];
#pragma unroll
      for (int r = 0; r < 4; ++r) {
        const int k = kbd + r;
        if ((unsigned)k < 8u) acc = fmaf(bs[d][r], swrow[k], acc);
      }
    }
    s3[tid] = acc;
  }
  __syncthreads();
  if (tid == 0) {
    const float mx = fmaxf(s3[0], fmaxf(s3[1], s3[2]));
    const float e0 = __expf(s3[0] - mx), e1 = __expf(s3[1] - mx), e2 = __expf(s3[2] - mx);
    const float inv = 1.0f / (e0 + e1 + e2);
    wout[0] = e0 * inv; wout[1] = e1 * inv; wout[2] = e2 * inv;
  }
}

// Stage C: one block per attention row i. Thread j computes the fused score
// s[i,j] = bias + sum_m w_m * kanLayer2_m(A_m[i] + B_m[j]); block softmax over
// j; target_att row = softmax @ target; then the two final 32->32 KAN layers.
__global__ __launch_bounds__(384) void stageC_kernel(
    const float* __restrict__ A, const float* __restrict__ Bt,
    const float* __restrict__ x2bw, const float* __restrict__ y2bw, const float* __restrict__ t2bw,
    const float* __restrict__ x2sw, const float* __restrict__ y2sw, const float* __restrict__ t2sw,
    const float* __restrict__ wv, const float* __restrict__ bias,
    const float* __restrict__ tg,
    const float* __restrict__ l1bw, const float* __restrict__ l1sw,
    const float* __restrict__ l2bw, const float* __restrict__ l2sw,
    float* __restrict__ out)
{
  __shared__ float sA[3][MM];
  __shared__ float sBW[3][MM];
  __shared__ float sSW[3][MM][14];   // layer-2 spline weights padded +3 zeros each side
  __shared__ float swv[4];           // w0, w1, w2, bias
  __shared__ float p[NN];
  __shared__ float redm[8], reds[8];
  __shared__ float part[12][HH];
  __shared__ float ta[HH];
  __shared__ float fsil[HH];
  __shared__ int   fkb[HH];
  __shared__ float fbs[HH][4];
  __shared__ float y1[HH];

  const int tid = threadIdx.x;
  const int i = blockIdx.x;

  // ---- load weights ----
  for (int idx = tid; idx < 3 * MM * 14; idx += 384) (&sSW[0][0][0])[idx] = 0.0f;
  __syncthreads();
  for (int idx = tid; idx < 3 * MM * 8; idx += 384) {
    const int m = idx / (MM * 8);
    const int rem = idx - m * (MM * 8);
    const int kk = rem >> 3, k = rem & 7;
    const float* src = (m == 0) ? x2sw : ((m == 1) ? y2sw : t2sw);
    sSW[m][kk][3 + k] = src[rem];
  }
  if (tid < 3 * MM) {
    const int m = tid / MM, o = tid - m * MM;
    sA[m][o] = A[(m * NN + i) * MM + o];
    const float* bsrc = (m == 0) ? x2bw : ((m == 1) ? y2bw : t2bw);
    sBW[m][o] = bsrc[o];
  }
  if (tid == 0) { swv[0] = wv[0]; swv[1] = wv[1]; swv[2] = wv[2]; swv[3] = bias[0]; }
  __syncthreads();

  // ---- fused pair score (layer-2 KAN, 3 modalities) ----
  float stot = swv[3];
#pragma unroll
  for (int m = 0; m < 3; ++m) {
    const float* Btm = Bt + (size_t)m * MM * NN;
    float acc = 0.0f;
    for (int k = 0; k < MM; ++k) {
      const float z = sA[m][k] + Btm[k * NN + tid];   // coalesced
      const float sig = 1.0f / (1.0f + __expf(-z));
      acc = fmaf(z * sig, sBW[m][k], acc);
      const float u = (z + 1.0f) * 2.5f;
      const float fu = floorf(u);
      const bool valid = (fu >= -3.0f) && (fu <= 7.0f);
      const float s = valid ? (1.0f / 6.0f) : 0.0f;
      const int c = valid ? ((int)fu + 3) : 0;
      const float tt = u - fu;
      const float t2 = tt * tt, t3 = t2 * tt, omt = 1.0f - tt;
      const float* wp = &sSW[m][k][c];
      acc = fmaf(omt * omt * omt * s, wp[0], acc);
      acc = fmaf((3.0f * t3 - 6.0f * t2 + 4.0f) * s, wp[1], acc);
      acc = fmaf((-3.0f * t3 + 3.0f * t2 + 3.0f * tt + 1.0f) * s, wp[2], acc);
      acc = fmaf(t3 * s, wp[3], acc);
    }
    stot = fmaf(swv[m], acc, stot);
  }

  // ---- row softmax (max then sum; normalize folded into matvec) ----
  const int lane = tid & 63, wid = tid >> 6;
  float v = stot;
#pragma unroll
  for (int off = 32; off > 0; off >>= 1) v = fmaxf(v, __shfl_down(v, off));
  if (lane == 0) redm[wid] = v;
  __syncthreads();
  float mx = redm[0];
#pragma unroll
  for (int w = 1; w < 6; ++w) mx = fmaxf(mx, redm[w]);
  const float e = __expf(stot - mx);
  p[tid] = e;
  float sv = e;
#pragma unroll
  for (int off = 32; off > 0; off >>= 1) sv += __shfl_down(sv, off);
  if (lane == 0) reds[wid] = sv;
  __syncthreads();
  const float ssum = reds[0] + reds[1] + reds[2] + reds[3] + reds[4] + reds[5];
  const float inv = 1.0f / ssum;

  // ---- target_att row: (sum_j e_j * tg[j]) * inv ----
  const int d = tid & 31, g = tid >> 5;   // 12 groups x 32 dims
  float acc2 = 0.0f;
  for (int s2 = 0; s2 < 32; ++s2) {
    const int j = g * 32 + s2;
    acc2 = fmaf(p[j], tg[j * HH + d], acc2);  // coalesced over d
  }
  part[g][d] = acc2;
  __syncthreads();
  if (tid < HH) {
    float a = 0.0f;
#pragma unroll
    for (int gg = 0; gg < 12; ++gg) a += part[gg][tid];
    ta[tid] = a * inv;
  }
  __syncthreads();

  // ---- final KAN layer 1 (32 -> 32, relu) ----
  if (tid < HH) {
    float b[4]; float s; int k;
    featEval(ta[tid], s, k, b);
    fsil[tid] = s; fkb[tid] = k;
    fbs[tid][0] = b[0]; fbs[tid][1] = b[1]; fbs[tid][2] = b[2]; fbs[tid][3] = b[3];
  }
  __syncthreads();
  if (tid < HH) {
    float acc = 0.0f;
    for (int dd = 0; dd < HH; ++dd) {
      acc = fmaf(fsil[dd], l1bw[tid * HH + dd], acc);
      const float* swrow = l1sw + ((size_t)(tid * HH + dd) << 3);
      const int kbd = fkb[dd];
#pragma unroll
      for (int r = 0; r < 4; ++r) {
        const int k = kbd + r;
        if ((unsigned)k < 8u) acc = fmaf(fbs[dd][r], swrow[k], acc);
      }
    }
    y1[tid] = fmaxf(acc, 0.0f);
  }
  __syncthreads();

  // ---- final KAN layer 2 (32 -> 32, relu) ----
  if (tid < HH) {
    float b[4]; float s; int k;
    featEval(y1[tid], s, k, b);
    fsil[tid] = s; fkb[tid] = k;
    fbs[tid][0] = b[0]; fbs[tid][1] = b[1]; fbs[tid][2] = b[2]; fbs[tid][3] = b[3];
  }
  __syncthreads();
  if (tid < HH) {
    float acc = 0.0f;
    for (int dd = 0; dd < HH; ++dd) {
      acc = fmaf(fsil[dd], l2bw[tid * HH + dd], acc);
      const float* swrow = l2sw + ((size_t)(tid * HH + dd) << 3);
      const int kbd = fkb[dd];
#pragma unroll
      for (int r = 0; r < 4; ++r) {
        const int k = kbd + r;
        if ((unsigned)k < 8u) acc = fmaf(fbs[dd][r], swrow[k], acc);
      }
    }
    out[i * HH + tid] = fmaxf(acc, 0.0f);
  }
}

extern "C" void kernel_launch(void* const* d_in, const int* in_sizes, int n_in,
                              void* d_out, int out_size, void* d_ws, size_t ws_size,
                              hipStream_t stream)
{
  const float* x    = (const float*)d_in[0];
  const float* y    = (const float*)d_in[1];
  const float* tg   = (const float*)d_in[2];
  const float* bias = (const float*)d_in[3];
  const float* x1bw = (const float*)d_in[4];
  const float* x1sw = (const float*)d_in[5];
  const float* x2bw = (const float*)d_in[6];
  const float* x2sw = (const float*)d_in[7];
  const float* y1bw = (const float*)d_in[8];
  const float* y1sw = (const float*)d_in[9];
  const float* y2bw = (const float*)d_in[10];
  const float* y2sw = (const float*)d_in[11];
  const float* t1bw = (const float*)d_in[12];
  const float* t1sw = (const float*)d_in[13];
  const float* t2bw = (const float*)d_in[14];
  const float* t2sw = (const float*)d_in[15];
  const float* f1bw = (const float*)d_in[16];
  const float* f1sw = (const float*)d_in[17];
  const float* f2bw = (const float*)d_in[18];
  const float* f2sw = (const float*)d_in[19];
  const float* l1bw = (const float*)d_in[20];
  const float* l1sw = (const float*)d_in[21];
  const float* l2bw = (const float*)d_in[22];
  const float* l2sw = (const float*)d_in[23];
  float* out = (float*)d_out;

  float* ws = (float*)d_ws;
  float* A  = ws;                 // [3][384][50]
  float* Bt = ws + 3 * NN * MM;   // [3][50][384]
  float* wv = ws + 6 * NN * MM;   // [3] fusion weights

  kanAB_kernel<<<NN, 128, 0, stream>>>(x,  x1bw, x1sw, A,              Bt);
  kanAB_kernel<<<NN, 128, 0, stream>>>(y,  y1bw, y1sw, A + NN * MM,    Bt + MM * NN);
  kanAB_kernel<<<NN, 128, 0, stream>>>(tg, t1bw, t1sw, A + 2 * NN * MM, Bt + 2 * MM * NN);
  fusion_kernel<<<1, 128, 0, stream>>>(x, y, tg, f1bw, f1sw, f2bw, f2sw, wv);
  stageC_kernel<<<NN, 384, 0, stream>>>(A, Bt, x2bw, y2bw, t2bw, x2sw, y2sw, t2sw,
                                        wv, bias, tg, l1bw, l1sw, l2bw, l2sw, out);
}

// Round 2
// 188.443 us; speedup vs baseline: 1.0767x; 1.0767x over previous
//
#include <hip/hip_runtime.h>

#define NN 384
#define HH 32
#define MM 50

// Closed-form cardinal cubic B-spline features for the efficient-kan uniform
// grid: GRID_SIZE=5, SPLINE_ORDER=3, h=0.4, knots g[c]=(c-3)*h-1, c=0..11.
// Valid domain x in [-2.2, 2.2); outside -> zero basis (s=0).
__device__ __forceinline__ void featEval(float x, float& sil, int& kb, float b[4]) {
  sil = x / (1.0f + __expf(-x));                  // silu
  const float u  = (x + 1.0f) * 2.5f;
  const float fu = floorf(u);
  const bool valid = (fu >= -3.0f) && (fu <= 7.0f);
  const float s = valid ? (1.0f / 6.0f) : 0.0f;
  kb = valid ? (int)fu : 100;
  const float tt = u - fu;
  const float t2 = tt * tt, t3 = t2 * tt, omt = 1.0f - tt;
  b[0] = omt * omt * omt * s;
  b[1] = (3.0f * t3 - 6.0f * t2 + 4.0f) * s;
  b[2] = (-3.0f * t3 + 3.0f * t2 + 3.0f * tt + 1.0f) * s;
  b[3] = t3 * s;
}

// Single-z KAN unit eval against a 14-wide zero-padded spline row (pad 3 each
// side): returns bw*silu(z) + sum_r basis_r * sw[k_r]. No predication.
__device__ __forceinline__ float kanEval(float z, float bwv, const float* __restrict__ wrow) {
  const float sig = 1.0f / (1.0f + __expf(-z));
  float r = z * sig * bwv;
  const float u  = (z + 1.0f) * 2.5f;
  const float fu = floorf(u);
  const bool valid = (fu >= -3.0f) && (fu <= 7.0f);
  const float s = valid ? (1.0f / 6.0f) : 0.0f;
  const int c = valid ? ((int)fu + 3) : 0;
  const float tt = u - fu;
  const float t2 = tt * tt, t3 = t2 * tt, omt = 1.0f - tt;
  const float* wp = wrow + c;
  r = fmaf(omt * omt * omt * s, wp[0], r);
  r = fmaf((3.0f * t3 - 6.0f * t2 + 4.0f) * s, wp[1], r);
  r = fmaf((-3.0f * t3 + 3.0f * t2 + 3.0f * tt + 1.0f) * s, wp[2], r);
  r = fmaf(t3 * s, wp[3], r);
  return r;
}

// Layer-1 decomposition, all 3 modalities in one launch: grid (384, 3).
// A[m][i][o] = first-half cols on row i; Bt[m][o][j] = second-half cols on
// row j, transposed for coalesced score-kernel reads.
__global__ __launch_bounds__(128) void kanAB_kernel(
    const float* __restrict__ x, const float* __restrict__ y, const float* __restrict__ tg,
    const float* __restrict__ xbw, const float* __restrict__ xsw,
    const float* __restrict__ ybw, const float* __restrict__ ysw,
    const float* __restrict__ tbw, const float* __restrict__ tsw,
    float* __restrict__ A, float* __restrict__ Bt)
{
  __shared__ float s_sil[HH];
  __shared__ int   s_kb[HH];
  __shared__ float s_b[HH][4];
  const int tid = threadIdx.x;
  const int i = blockIdx.x;
  const int m = blockIdx.y;
  const float* q  = (m == 0) ? x   : ((m == 1) ? y   : tg);
  const float* bw = (m == 0) ? xbw : ((m == 1) ? ybw : tbw);
  const float* sw = (m == 0) ? xsw : ((m == 1) ? ysw : tsw);
  if (tid < HH) {
    float b[4]; float sil; int kb;
    featEval(q[i * HH + tid], sil, kb, b);
    s_sil[tid] = sil; s_kb[tid] = kb;
    s_b[tid][0] = b[0]; s_b[tid][1] = b[1]; s_b[tid][2] = b[2]; s_b[tid][3] = b[3];
  }
  __syncthreads();
  const int half = tid >> 6;      // 0 -> A (cols 0..31), 1 -> B (cols 32..63)
  const int o = tid & 63;
  if (o < MM) {
    const int colbase = half * HH;
    float acc0 = 0.0f, acc1 = 0.0f;
    for (int d = 0; d < HH; d += 2) {
      {
        const int col = colbase + d;
        acc0 = fmaf(s_sil[d], bw[o * (2 * HH) + col], acc0);
        const float* swrow = sw + ((size_t)(o * (2 * HH) + col) << 3);
        const int kb = s_kb[d];
#pragma unroll
        for (int r = 0; r < 4; ++r) {
          const int k = kb + r;
          if ((unsigned)k < 8u) acc0 = fmaf(s_b[d][r], swrow[k], acc0);
        }
      }
      {
        const int col = colbase + d + 1;
        acc1 = fmaf(s_sil[d + 1], bw[o * (2 * HH) + col], acc1);
        const float* swrow = sw + ((size_t)(o * (2 * HH) + col) << 3);
        const int kb = s_kb[d + 1];
#pragma unroll
        for (int r = 0; r < 4; ++r) {
          const int k = kb + r;
          if ((unsigned)k < 8u) acc1 = fmaf(s_b[d + 1][r], swrow[k], acc1);
        }
      }
    }
    const float acc = acc0 + acc1;
    if (half == 0) A[((size_t)m * NN + i) * MM + o] = acc;
    else           Bt[((size_t)m * MM + o) * NN + i] = acc;
  }
}

// Dynamic modal fusion weights. One block, 384 threads; mean reduction split
// 4-way per column for parallelism.
__global__ __launch_bounds__(384) void fusion_kernel(
    const float* __restrict__ x, const float* __restrict__ y, const float* __restrict__ tg,
    const float* __restrict__ f1bw, const float* __restrict__ f1sw,
    const float* __restrict__ f2bw, const float* __restrict__ f2sw,
    float* __restrict__ wout)
{
  __shared__ float partial[3][4][HH];
  __shared__ float sil[96];
  __shared__ int   kb[96];
  __shared__ float bs[96][4];
  __shared__ float z1[MM];
  __shared__ float s3[3];
  const int tid = threadIdx.x;
  {
    const int mm = tid >> 7;        // 0..2
    const int sub = tid & 127;
    const int prt = sub >> 5;       // 0..3
    const int col = sub & 31;
    const float* src = (mm == 0) ? x : ((mm == 1) ? y : tg);
    float acc = 0.0f;
    for (int r = prt; r < NN; r += 4) acc += src[r * HH + col];
    partial[mm][prt][col] = acc;
  }
  __syncthreads();
  if (tid < 96) {
    const int mm = tid >> 5, col = tid & 31;
    const float fv = (partial[mm][0][col] + partial[mm][1][col] +
                      partial[mm][2][col] + partial[mm][3][col]) * (1.0f / NN);
    float b[4]; float s; int k;
    featEval(fv, s, k, b);
    sil[tid] = s; kb[tid] = k;
    bs[tid][0] = b[0]; bs[tid][1] = b[1]; bs[tid][2] = b[2]; bs[tid][3] = b[3];
  }
  __syncthreads();
  if (tid < MM) {
    float acc = 0.0f;
    for (int d = 0; d < 96; ++d) {
      acc = fmaf(sil[d], f1bw[tid * 96 + d], acc);
      const float* swrow = f1sw + ((size_t)(tid * 96 + d) << 3);
      const int kbd = kb[d];
#pragma unroll
      for (int r = 0; r < 4; ++r) {
        const int k = kbd + r;
        if ((unsigned)k < 8u) acc = fmaf(bs[d][r], swrow[k], acc);
      }
    }
    z1[tid] = acc;
  }
  __syncthreads();
  if (tid < MM) {
    float b[4]; float s; int k;
    featEval(z1[tid], s, k, b);
    sil[tid] = s; kb[tid] = k;
    bs[tid][0] = b[0]; bs[tid][1] = b[1]; bs[tid][2] = b[2]; bs[tid][3] = b[3];
  }
  __syncthreads();
  if (tid < 3) {
    float acc = 0.0f;
    for (int d = 0; d < MM; ++d) {
      acc = fmaf(sil[d], f2bw[tid * MM + d], acc);
      const float* swrow = f2sw + ((size_t)(tid * MM + d) << 3);
      const int kbd = kb[d];
#pragma unroll
      for (int r = 0; r < 4; ++r) {
        const int k = kbd + r;
        if ((unsigned)k < 8u) acc = fmaf(bs[d][r], swrow[k], acc);
      }
    }
    s3[tid] = acc;
  }
  __syncthreads();
  if (tid == 0) {
    const float mx = fmaxf(s3[0], fmaxf(s3[1], s3[2]));
    const float e0 = __expf(s3[0] - mx), e1 = __expf(s3[1] - mx), e2 = __expf(s3[2] - mx);
    const float inv = 1.0f / (e0 + e1 + e2);
    wout[0] = e0 * inv; wout[1] = e1 * inv; wout[2] = e2 * inv;
  }
}

// Per-modality layer-2 KAN over all pairs: grid (384 rows, 3 modalities),
// 384 threads (one per column j). Sp[m][i][j] = kanLayer2_m(A_m[i]+B_m[j]).
// 2-way k-unroll with independent accumulator chains for ILP.
__global__ __launch_bounds__(384) void score_kernel(
    const float* __restrict__ A, const float* __restrict__ Bt,
    const float* __restrict__ x2bw, const float* __restrict__ y2bw, const float* __restrict__ t2bw,
    const float* __restrict__ x2sw, const float* __restrict__ y2sw, const float* __restrict__ t2sw,
    float* __restrict__ Sp)
{
  __shared__ float sA[MM];
  __shared__ float sBW[MM];
  __shared__ float sSW[MM][14];   // zero-padded +3 each side
  const int tid = threadIdx.x;
  const int i = blockIdx.x;
  const int m = blockIdx.y;
  const float* bsrc = (m == 0) ? x2bw : ((m == 1) ? y2bw : t2bw);
  const float* ssrc = (m == 0) ? x2sw : ((m == 1) ? y2sw : t2sw);

  // pad zeros (indices 0..2, 11..13 of each row) and fill interior (3..10);
  // writers disjoint -> single barrier.
  for (int idx = tid; idx < MM * 6; idx += 384) {
    const int kk = idx / 6, r = idx - kk * 6;
    sSW[kk][(r < 3) ? r : (r + 8)] = 0.0f;
  }
  for (int idx = tid; idx < MM * 8; idx += 384) {
    sSW[idx >> 3][3 + (idx & 7)] = ssrc[idx];
  }
  if (tid < MM) {
    sA[tid]  = A[((size_t)m * NN + i) * MM + tid];
    sBW[tid] = bsrc[tid];
  }
  __syncthreads();

  const float* BtBase = Bt + (size_t)m * MM * NN + tid;
  float acc0 = 0.0f, acc1 = 0.0f;
  for (int k = 0; k < MM; k += 2) {
    const float z0 = sA[k]     + BtBase[(size_t)k * NN];
    const float z1 = sA[k + 1] + BtBase[(size_t)(k + 1) * NN];
    acc0 += kanEval(z0, sBW[k],     &sSW[k][0]);
    acc1 += kanEval(z1, sBW[k + 1], &sSW[k + 1][0]);
  }
  Sp[((size_t)m * NN + i) * NN + tid] = acc0 + acc1;
}

// Row kernel: weighted fuse of 3 score planes + bias, row softmax, @target,
// two final 32->32 KAN layers with relu. One block per row.
__global__ __launch_bounds__(384) void row_kernel(
    const float* __restrict__ Sp, const float* __restrict__ wv, const float* __restrict__ bias,
    const float* __restrict__ tg,
    const float* __restrict__ l1bw, const float* __restrict__ l1sw,
    const float* __restrict__ l2bw, const float* __restrict__ l2sw,
    float* __restrict__ out)
{
  __shared__ float p[NN];
  __shared__ float redm[8], reds[8];
  __shared__ float part[12][HH];
  __shared__ float ta[HH];
  __shared__ float fsil[HH];
  __shared__ int   fkb[HH];
  __shared__ float fbs[HH][4];
  __shared__ float y1v[HH];
  const int tid = threadIdx.x;
  const int i = blockIdx.x;

  float stot = bias[0];
  stot = fmaf(wv[0], Sp[(size_t)i * NN + tid], stot);
  stot = fmaf(wv[1], Sp[((size_t)NN + i) * NN + tid], stot);
  stot = fmaf(wv[2], Sp[((size_t)2 * NN + i) * NN + tid], stot);

  // ---- row softmax ----
  const int lane = tid & 63, wid = tid >> 6;
  float v = stot;
#pragma unroll
  for (int off = 32; off > 0; off >>= 1) v = fmaxf(v, __shfl_down(v, off));
  if (lane == 0) redm[wid] = v;
  __syncthreads();
  float mx = redm[0];
#pragma unroll
  for (int w = 1; w < 6; ++w) mx = fmaxf(mx, redm[w]);
  const float e = __expf(stot - mx);
  p[tid] = e;
  float sv = e;
#pragma unroll
  for (int off = 32; off > 0; off >>= 1) sv += __shfl_down(sv, off);
  if (lane == 0) reds[wid] = sv;
  __syncthreads();
  const float ssum = reds[0] + reds[1] + reds[2] + reds[3] + reds[4] + reds[5];
  const float inv = 1.0f / ssum;

  // ---- target_att row ----
  const int d = tid & 31, g = tid >> 5;
  float acc2 = 0.0f;
  for (int s2 = 0; s2 < 32; ++s2) {
    const int j = g * 32 + s2;
    acc2 = fmaf(p[j], tg[j * HH + d], acc2);
  }
  part[g][d] = acc2;
  __syncthreads();
  if (tid < HH) {
    float a = 0.0f;
#pragma unroll
    for (int gg = 0; gg < 12; ++gg) a += part[gg][tid];
    ta[tid] = a * inv;
  }
  __syncthreads();

  // ---- final KAN layer 1 (32 -> 32, relu) ----
  if (tid < HH) {
    float b[4]; float s; int k;
    featEval(ta[tid], s, k, b);
    fsil[tid] = s; fkb[tid] = k;
    fbs[tid][0] = b[0]; fbs[tid][1] = b[1]; fbs[tid][2] = b[2]; fbs[tid][3] = b[3];
  }
  __syncthreads();
  if (tid < HH) {
    float acc = 0.0f;
    for (int dd = 0; dd < HH; ++dd) {
      acc = fmaf(fsil[dd], l1bw[tid * HH + dd], acc);
      const float* swrow = l1sw + ((size_t)(tid * HH + dd) << 3);
      const int kbd = fkb[dd];
#pragma unroll
      for (int r = 0; r < 4; ++r) {
        const int k = kbd + r;
        if ((unsigned)k < 8u) acc = fmaf(fbs[dd][r], swrow[k], acc);
      }
    }
    y1v[tid] = fmaxf(acc, 0.0f);
  }
  __syncthreads();

  // ---- final KAN layer 2 (32 -> 32, relu) ----
  if (tid < HH) {
    float b[4]; float s; int k;
    featEval(y1v[tid], s, k, b);
    fsil[tid] = s; fkb[tid] = k;
    fbs[tid][0] = b[0]; fbs[tid][1] = b[1]; fbs[tid][2] = b[2]; fbs[tid][3] = b[3];
  }
  __syncthreads();
  if (tid < HH) {
    float acc = 0.0f;
    for (int dd = 0; dd < HH; ++dd) {
      acc = fmaf(fsil[dd], l2bw[tid * HH + dd], acc);
      const float* swrow = l2sw + ((size_t)(tid * HH + dd) << 3);
      const int kbd = fkb[dd];
#pragma unroll
      for (int r = 0; r < 4; ++r) {
        const int k = kbd + r;
        if ((unsigned)k < 8u) acc = fmaf(fbs[dd][r], swrow[k], acc);
      }
    }
    out[i * HH + tid] = fmaxf(acc, 0.0f);
  }
}

extern "C" void kernel_launch(void* const* d_in, const int* in_sizes, int n_in,
                              void* d_out, int out_size, void* d_ws, size_t ws_size,
                              hipStream_t stream)
{
  const float* x    = (const float*)d_in[0];
  const float* y    = (const float*)d_in[1];
  const float* tg   = (const float*)d_in[2];
  const float* bias = (const float*)d_in[3];
  const float* x1bw = (const float*)d_in[4];
  const float* x1sw = (const float*)d_in[5];
  const float* x2bw = (const float*)d_in[6];
  const float* x2sw = (const float*)d_in[7];
  const float* y1bw = (const float*)d_in[8];
  const float* y1sw = (const float*)d_in[9];
  const float* y2bw = (const float*)d_in[10];
  const float* y2sw = (const float*)d_in[11];
  const float* t1bw = (const float*)d_in[12];
  const float* t1sw = (const float*)d_in[13];
  const float* t2bw = (const float*)d_in[14];
  const float* t2sw = (const float*)d_in[15];
  const float* f1bw = (const float*)d_in[16];
  const float* f1sw = (const float*)d_in[17];
  const float* f2bw = (const float*)d_in[18];
  const float* f2sw = (const float*)d_in[19];
  const float* l1bw = (const float*)d_in[20];
  const float* l1sw = (const float*)d_in[21];
  const float* l2bw = (const float*)d_in[22];
  const float* l2sw = (const float*)d_in[23];
  float* out = (float*)d_out;

  float* ws = (float*)d_ws;
  float* A  = ws;                          // [3][384][50]
  float* Bt = ws + 3 * NN * MM;            // [3][50][384]
  float* Sp = ws + 6 * NN * MM;            // [3][384][384]
  float* wv = Sp + 3 * NN * NN;            // [3]

  kanAB_kernel<<<dim3(NN, 3), 128, 0, stream>>>(x, y, tg, x1bw, x1sw, y1bw, y1sw,
                                                t1bw, t1sw, A, Bt);
  fusion_kernel<<<1, 384, 0, stream>>>(x, y, tg, f1bw, f1sw, f2bw, f2sw, wv);
  score_kernel<<<dim3(NN, 3), 384, 0, stream>>>(A, Bt, x2bw, y2bw, t2bw,
                                                x2sw, y2sw, t2sw, Sp);
  row_kernel<<<NN, 384, 0, stream>>>(Sp, wv, bias, tg, l1bw, l1sw, l2bw, l2sw, out);
}

// Round 3
// 127.576 us; speedup vs baseline: 1.5904x; 1.4771x over previous
//
#include <hip/hip_runtime.h>

#define NN 384
#define HH 32
#define MM 50

__device__ __forceinline__ float fastRcp(float x) { return __builtin_amdgcn_rcpf(x); }

// Closed-form cardinal cubic B-spline features for the efficient-kan uniform
// grid: GRID_SIZE=5, SPLINE_ORDER=3, h=0.4, knots g[c]=(c-3)*h-1, c=0..11.
// Valid domain x in [-2.2, 2.2); outside -> zero basis (s=0), kb=100 sentinel.
__device__ __forceinline__ void featEval(float x, float& sil, int& kb, float b[4]) {
  sil = x * fastRcp(1.0f + __expf(-x));           // silu
  const float u  = (x + 1.0f) * 2.5f;
  const float fu = floorf(u);
  const bool valid = (fu >= -3.0f) && (fu <= 7.0f);
  const float s = valid ? (1.0f / 6.0f) : 0.0f;
  kb = valid ? (int)fu : 100;
  const float tt = u - fu;
  const float t2 = tt * tt, t3 = t2 * tt, omt = 1.0f - tt;
  b[0] = omt * omt * omt * s;
  b[1] = (3.0f * t3 - 6.0f * t2 + 4.0f) * s;
  b[2] = (-3.0f * t3 + 3.0f * t2 + 3.0f * tt + 1.0f) * s;
  b[3] = t3 * s;
}

// Layer-1 decomposition, all 3 modalities in one launch: grid (384, 3).
// A[m][i][o] = first-half cols on row i; Bt[m][o][j] = second-half cols on
// row j, transposed for coalesced score-kernel reads.
__global__ __launch_bounds__(128) void kanAB_kernel(
    const float* __restrict__ x, const float* __restrict__ y, const float* __restrict__ tg,
    const float* __restrict__ xbw, const float* __restrict__ xsw,
    const float* __restrict__ ybw, const float* __restrict__ ysw,
    const float* __restrict__ tbw, const float* __restrict__ tsw,
    float* __restrict__ A, float* __restrict__ Bt)
{
  __shared__ float s_sil[HH];
  __shared__ int   s_kb[HH];
  __shared__ float s_b[HH][4];
  const int tid = threadIdx.x;
  const int i = blockIdx.x;
  const int m = blockIdx.y;
  const float* q  = (m == 0) ? x   : ((m == 1) ? y   : tg);
  const float* bw = (m == 0) ? xbw : ((m == 1) ? ybw : tbw);
  const float* sw = (m == 0) ? xsw : ((m == 1) ? ysw : tsw);
  if (tid < HH) {
    float b[4]; float sil; int kb;
    featEval(q[i * HH + tid], sil, kb, b);
    s_sil[tid] = sil; s_kb[tid] = kb;
    s_b[tid][0] = b[0]; s_b[tid][1] = b[1]; s_b[tid][2] = b[2]; s_b[tid][3] = b[3];
  }
  __syncthreads();
  const int half = tid >> 6;      // 0 -> A (cols 0..31), 1 -> B (cols 32..63)
  const int o = tid & 63;
  if (o < MM) {
    const int colbase = half * HH;
    float acc0 = 0.0f, acc1 = 0.0f;
    for (int d = 0; d < HH; d += 2) {
      {
        const int col = colbase + d;
        acc0 = fmaf(s_sil[d], bw[o * (2 * HH) + col], acc0);
        const float* swrow = sw + ((size_t)(o * (2 * HH) + col) << 3);
        const int kb = s_kb[d];
#pragma unroll
        for (int r = 0; r < 4; ++r) {
          const int k = kb + r;
          if ((unsigned)k < 8u) acc0 = fmaf(s_b[d][r], swrow[k], acc0);
        }
      }
      {
        const int col = colbase + d + 1;
        acc1 = fmaf(s_sil[d + 1], bw[o * (2 * HH) + col], acc1);
        const float* swrow = sw + ((size_t)(o * (2 * HH) + col) << 3);
        const int kb = s_kb[d + 1];
#pragma unroll
        for (int r = 0; r < 4; ++r) {
          const int k = kb + r;
          if ((unsigned)k < 8u) acc1 = fmaf(s_b[d + 1][r], swrow[k], acc1);
        }
      }
    }
    const float acc = acc0 + acc1;
    if (half == 0) A[((size_t)m * NN + i) * MM + o] = acc;
    else           Bt[((size_t)m * MM + o) * NN + i] = acc;
  }
}

// Dynamic modal fusion weights. One block, 384 threads. All phases use dense,
// coalesced loads: the sparse 4-wide spline window is expanded into a dense
// zero-filled basis vector in LDS, turning layer eval into plain dot products
// (one wave per output, shuffle-reduced).
__global__ __launch_bounds__(384) void fusion_kernel(
    const float* __restrict__ x, const float* __restrict__ y, const float* __restrict__ tg,
    const float* __restrict__ f1bw, const float* __restrict__ f1sw,
    const float* __restrict__ f2bw, const float* __restrict__ f2sw,
    float* __restrict__ wout)
{
  __shared__ float4 part4[3][8][16];
  __shared__ float sil[96];
  __shared__ float sb8[96][8];
  __shared__ float z1[MM];
  __shared__ float sil2[MM];
  __shared__ float sb8b[MM][8];
  __shared__ float s3[3];
  const int tid = threadIdx.x;
  const int lane = tid & 63, w = tid >> 6;

  // ---- phase A: column means, float4-vectorized, 16-way split per column-quad
  {
    const int mm = tid >> 7;        // 0..2
    const int sub = tid & 127;
    const int q = sub >> 4;         // 0..7 float4 chunk
    const int prt = sub & 15;       // 0..15
    const float* src = (mm == 0) ? x : ((mm == 1) ? y : tg);
    const float4* s4 = (const float4*)src;
    float4 a = make_float4(0.f, 0.f, 0.f, 0.f);
    for (int r = prt; r < NN; r += 16) {
      const float4 v = s4[r * 8 + q];
      a.x += v.x; a.y += v.y; a.z += v.z; a.w += v.w;
    }
    part4[mm][q][prt] = a;
  }
  // zero dense basis buffers (disjoint from part4 writes)
  for (int idx = tid; idx < 96 * 8; idx += 384) (&sb8[0][0])[idx] = 0.0f;
  for (int idx = tid; idx < MM * 8; idx += 384) (&sb8b[0][0])[idx] = 0.0f;
  __syncthreads();

  // ---- phase B: finish means, build sil + dense basis sb8
  if (tid < 96) {
    const int mm = tid >> 5, col = tid & 31;
    const int q = col >> 2, comp = col & 3;
    const float* pp = (const float*)&part4[mm][q][0];
    float v = 0.0f;
#pragma unroll
    for (int prt = 0; prt < 16; ++prt) v += pp[prt * 4 + comp];
    const float fv = v * (1.0f / NN);
    float b[4]; float s; int kb;
    featEval(fv, s, kb, b);
    sil[tid] = s;
#pragma unroll
    for (int r = 0; r < 4; ++r) {
      const int k = kb + r;
      if ((unsigned)k < 8u) sb8[tid][k] = b[r];
    }
  }
  __syncthreads();

  // ---- layer 1: z1[o] = f1bw[o,:].sil + f1sw[o,:,:].sb8 (dense, coalesced)
  {
    const float* sbf = &sb8[0][0];
    for (int p = 0; p < 9; ++p) {
      const int o = p * 6 + w;
      float acc = 0.0f;
      if (o < MM) {
        const float* swrow = f1sw + (size_t)o * (96 * 8);
#pragma unroll
        for (int e = lane; e < 96 * 8; e += 64) acc = fmaf(swrow[e], sbf[e], acc);
        const float* bwrow = f1bw + (size_t)o * 96;
#pragma unroll
        for (int e = lane; e < 96; e += 64) acc = fmaf(bwrow[e], sil[e], acc);
      }
#pragma unroll
      for (int off = 32; off > 0; off >>= 1) acc += __shfl_down(acc, off);
      if (lane == 0 && o < MM) z1[o] = acc;
    }
  }
  __syncthreads();

  // ---- hidden activation features
  if (tid < MM) {
    float b[4]; float s; int kb;
    featEval(z1[tid], s, kb, b);
    sil2[tid] = s;
#pragma unroll
    for (int r = 0; r < 4; ++r) {
      const int k = kb + r;
      if ((unsigned)k < 8u) sb8b[tid][k] = b[r];
    }
  }
  __syncthreads();

  // ---- layer 2: 3 outputs, one wave each
  if (w < 3) {
    const float* sbf = &sb8b[0][0];
    float acc = 0.0f;
    const float* swrow = f2sw + (size_t)w * (MM * 8);
#pragma unroll
    for (int e = lane; e < MM * 8; e += 64) acc = fmaf(swrow[e], sbf[e], acc);
    const float* bwrow = f2bw + (size_t)w * MM;
    if (lane < MM) acc = fmaf(bwrow[lane], sil2[lane], acc);
#pragma unroll
    for (int off = 32; off > 0; off >>= 1) acc += __shfl_down(acc, off);
    if (lane == 0) s3[w] = acc;
  }
  __syncthreads();

  if (tid == 0) {
    const float mx = fmaxf(s3[0], fmaxf(s3[1], s3[2]));
    const float e0 = __expf(s3[0] - mx), e1 = __expf(s3[1] - mx), e2 = __expf(s3[2] - mx);
    const float inv = fastRcp(e0 + e1 + e2);
    wout[0] = e0 * inv; wout[1] = e1 * inv; wout[2] = e2 * inv;
  }
}

// Per-modality layer-2 KAN over all pairs: grid (384 rows, 3 modalities),
// 384 threads (one per column j). Sp[m][i][j] = kanLayer2_m(A_m[i]+B_m[j]).
// The spline is evaluated as a piecewise cubic via precomputed per-cell
// Horner coefficients (cells 1..11 real, 0 and 12 zero sentinels so the
// clamped cell index makes out-of-domain inputs evaluate to exactly 0).
__global__ __launch_bounds__(384) void score_kernel(
    const float* __restrict__ A, const float* __restrict__ Bt,
    const float* __restrict__ x2bw, const float* __restrict__ y2bw, const float* __restrict__ t2bw,
    const float* __restrict__ x2sw, const float* __restrict__ y2sw, const float* __restrict__ t2sw,
    float* __restrict__ Sp)
{
  __shared__ float sA[MM];
  __shared__ float sBW[MM];
  __shared__ float pad[MM][14];     // spline weights zero-padded +3 each side
  __shared__ float4 coef[MM][13];   // per-cell cubic coeffs (a0,a1,a2,a3)
  const int tid = threadIdx.x;
  const int i = blockIdx.x;
  const int m = blockIdx.y;
  const float* bsrc = (m == 0) ? x2bw : ((m == 1) ? y2bw : t2bw);
  const float* ssrc = (m == 0) ? x2sw : ((m == 1) ? y2sw : t2sw);

  for (int idx = tid; idx < MM * 6; idx += 384) {
    const int kk = idx / 6, r = idx - kk * 6;
    pad[kk][(r < 3) ? r : (r + 8)] = 0.0f;
  }
  for (int idx = tid; idx < MM * 8; idx += 384) {
    pad[idx >> 3][3 + (idx & 7)] = ssrc[idx];
  }
  if (tid < MM) {
    sA[tid]  = A[((size_t)m * NN + i) * MM + tid];
    sBW[tid] = bsrc[tid];
  }
  __syncthreads();

  // fold spline weights through the cardinal-basis matrix -> cubic coeffs
  for (int idx = tid; idx < MM * 11; idx += 384) {
    const int k = idx / 11, cm1 = idx - k * 11;   // cell-1: 0..10
    const float* bp = &pad[k][cm1];
    const float p0 = bp[0], p1 = bp[1], p2 = bp[2], p3 = bp[3];
    const float a0 = (p0 + 4.0f * p1 + p2) * (1.0f / 6.0f);
    const float a1 = (p2 - p0) * 0.5f;
    const float a2 = (p0 - 2.0f * p1 + p2) * 0.5f;
    const float a3 = (p3 - p0) * (1.0f / 6.0f) + (p1 - p2) * 0.5f;
    coef[k][cm1 + 1] = make_float4(a0, a1, a2, a3);
  }
  if (tid < MM * 2) {
    coef[tid >> 1][(tid & 1) * 12] = make_float4(0.f, 0.f, 0.f, 0.f);
  }
  __syncthreads();

  const float* BtBase = Bt + (size_t)m * MM * NN + tid;
  float acc0 = 0.0f, acc1 = 0.0f;
  for (int k = 0; k < MM; k += 2) {
    const float z0 = sA[k]     + BtBase[(size_t)k * NN];
    const float z1 = sA[k + 1] + BtBase[(size_t)(k + 1) * NN];
    {
      const float u = fmaf(z0, 2.5f, 2.5f);
      const float fu = floorf(u);
      const float t = u - fu;
      const int cc = (int)(fminf(fmaxf(fu, -4.0f), 8.0f)) + 4;
      const float4 C = coef[k][cc];
      acc0 += fmaf(t, fmaf(t, fmaf(t, C.w, C.z), C.y), C.x);
      const float sg = fastRcp(1.0f + __expf(-z0));
      acc0 = fmaf(z0 * sg, sBW[k], acc0);
    }
    {
      const float u = fmaf(z1, 2.5f, 2.5f);
      const float fu = floorf(u);
      const float t = u - fu;
      const int cc = (int)(fminf(fmaxf(fu, -4.0f), 8.0f)) + 4;
      const float4 C = coef[k + 1][cc];
      acc1 += fmaf(t, fmaf(t, fmaf(t, C.w, C.z), C.y), C.x);
      const float sg = fastRcp(1.0f + __expf(-z1));
      acc1 = fmaf(z1 * sg, sBW[k + 1], acc1);
    }
  }
  Sp[((size_t)m * NN + i) * NN + tid] = acc0 + acc1;
}

// Row kernel: weighted fuse of 3 score planes + bias, row softmax, @target,
// two final 32->32 KAN layers with relu. One block per row.
__global__ __launch_bounds__(384) void row_kernel(
    const float* __restrict__ Sp, const float* __restrict__ wv, const float* __restrict__ bias,
    const float* __restrict__ tg,
    const float* __restrict__ l1bw, const float* __restrict__ l1sw,
    const float* __restrict__ l2bw, const float* __restrict__ l2sw,
    float* __restrict__ out)
{
  __shared__ float p[NN];
  __shared__ float redm[8], reds[8];
  __shared__ float part[12][HH];
  __shared__ float ta[HH];
  __shared__ float fsil[HH];
  __shared__ int   fkb[HH];
  __shared__ float fbs[HH][4];
  __shared__ float y1v[HH];
  const int tid = threadIdx.x;
  const int i = blockIdx.x;

  float stot = bias[0];
  stot = fmaf(wv[0], Sp[(size_t)i * NN + tid], stot);
  stot = fmaf(wv[1], Sp[((size_t)NN + i) * NN + tid], stot);
  stot = fmaf(wv[2], Sp[((size_t)2 * NN + i) * NN + tid], stot);

  // ---- row softmax ----
  const int lane = tid & 63, wid = tid >> 6;
  float v = stot;
#pragma unroll
  for (int off = 32; off > 0; off >>= 1) v = fmaxf(v, __shfl_down(v, off));
  if (lane == 0) redm[wid] = v;
  __syncthreads();
  float mx = redm[0];
#pragma unroll
  for (int w = 1; w < 6; ++w) mx = fmaxf(mx, redm[w]);
  const float e = __expf(stot - mx);
  p[tid] = e;
  float sv = e;
#pragma unroll
  for (int off = 32; off > 0; off >>= 1) sv += __shfl_down(sv, off);
  if (lane == 0) reds[wid] = sv;
  __syncthreads();
  const float ssum = reds[0] + reds[1] + reds[2] + reds[3] + reds[4] + reds[5];
  const float inv = 1.0f / ssum;

  // ---- target_att row ----
  const int d = tid & 31, g = tid >> 5;
  float acc2 = 0.0f;
  for (int s2 = 0; s2 < 32; ++s2) {
    const int j = g * 32 + s2;
    acc2 = fmaf(p[j], tg[j * HH + d], acc2);
  }
  part[g][d] = acc2;
  __syncthreads();
  if (tid < HH) {
    float a = 0.0f;
#pragma unroll
    for (int gg = 0; gg < 12; ++gg) a += part[gg][tid];
    ta[tid] = a * inv;
  }
  __syncthreads();

  // ---- final KAN layer 1 (32 -> 32, relu) ----
  if (tid < HH) {
    float b[4]; float s; int k;
    featEval(ta[tid], s, k, b);
    fsil[tid] = s; fkb[tid] = k;
    fbs[tid][0] = b[0]; fbs[tid][1] = b[1]; fbs[tid][2] = b[2]; fbs[tid][3] = b[3];
  }
  __syncthreads();
  if (tid < HH) {
    float acc = 0.0f;
    for (int dd = 0; dd < HH; ++dd) {
      acc = fmaf(fsil[dd], l1bw[tid * HH + dd], acc);
      const float* swrow = l1sw + ((size_t)(tid * HH + dd) << 3);
      const int kbd = fkb[dd];
#pragma unroll
      for (int r = 0; r < 4; ++r) {
        const int k = kbd + r;
        if ((unsigned)k < 8u) acc = fmaf(fbs[dd][r], swrow[k], acc);
      }
    }
    y1v[tid] = fmaxf(acc, 0.0f);
  }
  __syncthreads();

  // ---- final KAN layer 2 (32 -> 32, relu) ----
  if (tid < HH) {
    float b[4]; float s; int k;
    featEval(y1v[tid], s, k, b);
    fsil[tid] = s; fkb[tid] = k;
    fbs[tid][0] = b[0]; fbs[tid][1] = b[1]; fbs[tid][2] = b[2]; fbs[tid][3] = b[3];
  }
  __syncthreads();
  if (tid < HH) {
    float acc = 0.0f;
    for (int dd = 0; dd < HH; ++dd) {
      acc = fmaf(fsil[dd], l2bw[tid * HH + dd], acc);
      const float* swrow = l2sw + ((size_t)(tid * HH + dd) << 3);
      const int kbd = fkb[dd];
#pragma unroll
      for (int r = 0; r < 4; ++r) {
        const int k = kbd + r;
        if ((unsigned)k < 8u) acc = fmaf(fbs[dd][r], swrow[k], acc);
      }
    }
    out[i * HH + tid] = fmaxf(acc, 0.0f);
  }
}

extern "C" void kernel_launch(void* const* d_in, const int* in_sizes, int n_in,
                              void* d_out, int out_size, void* d_ws, size_t ws_size,
                              hipStream_t stream)
{
  const float* x    = (const float*)d_in[0];
  const float* y    = (const float*)d_in[1];
  const float* tg   = (const float*)d_in[2];
  const float* bias = (const float*)d_in[3];
  const float* x1bw = (const float*)d_in[4];
  const float* x1sw = (const float*)d_in[5];
  const float* x2bw = (const float*)d_in[6];
  const float* x2sw = (const float*)d_in[7];
  const float* y1bw = (const float*)d_in[8];
  const float* y1sw = (const float*)d_in[9];
  const float* y2bw = (const float*)d_in[10];
  const float* y2sw = (const float*)d_in[11];
  const float* t1bw = (const float*)d_in[12];
  const float* t1sw = (const float*)d_in[13];
  const float* t2bw = (const float*)d_in[14];
  const float* t2sw = (const float*)d_in[15];
  const float* f1bw = (const float*)d_in[16];
  const float* f1sw = (const float*)d_in[17];
  const float* f2bw = (const float*)d_in[18];
  const float* f2sw = (const float*)d_in[19];
  const float* l1bw = (const float*)d_in[20];
  const float* l1sw = (const float*)d_in[21];
  const float* l2bw = (const float*)d_in[22];
  const float* l2sw = (const float*)d_in[23];
  float* out = (float*)d_out;

  float* ws = (float*)d_ws;
  float* A  = ws;                          // [3][384][50]
  float* Bt = ws + 3 * NN * MM;            // [3][50][384]
  float* Sp = ws + 6 * NN * MM;            // [3][384][384]
  float* wv = Sp + 3 * NN * NN;            // [3]

  kanAB_kernel<<<dim3(NN, 3), 128, 0, stream>>>(x, y, tg, x1bw, x1sw, y1bw, y1sw,
                                                t1bw, t1sw, A, Bt);
  fusion_kernel<<<1, 384, 0, stream>>>(x, y, tg, f1bw, f1sw, f2bw, f2sw, wv);
  score_kernel<<<dim3(NN, 3), 384, 0, stream>>>(A, Bt, x2bw, y2bw, t2bw,
                                                x2sw, y2sw, t2sw, Sp);
  row_kernel<<<NN, 384, 0, stream>>>(Sp, wv, bias, tg, l1bw, l1sw, l2bw, l2sw, out);
}

// Round 4
// 64.748 us; speedup vs baseline: 3.1336x; 1.9703x over previous
//
#include <hip/hip_runtime.h>

#define NN 384
#define HH 32
#define MM 50

__device__ __forceinline__ float fastRcp(float x) { return __builtin_amdgcn_rcpf(x); }

// Closed-form cardinal cubic B-spline features for the efficient-kan uniform
// grid: GRID_SIZE=5, SPLINE_ORDER=3, h=0.4, knots g[c]=(c-3)*h-1, c=0..11.
// Valid domain x in [-2.2, 2.2); outside -> zero basis (s=0), kb=100 sentinel.
__device__ __forceinline__ void featEval(float x, float& sil, int& kb, float b[4]) {
  sil = x * fastRcp(1.0f + __expf(-x));           // silu
  const float u  = (x + 1.0f) * 2.5f;
  const float fu = floorf(u);
  const bool valid = (fu >= -3.0f) && (fu <= 7.0f);
  const float s = valid ? (1.0f / 6.0f) : 0.0f;
  kb = valid ? (int)fu : 100;
  const float tt = u - fu;
  const float t2 = tt * tt, t3 = t2 * tt, omt = 1.0f - tt;
  b[0] = omt * omt * omt * s;
  b[1] = (3.0f * t3 - 6.0f * t2 + 4.0f) * s;
  b[2] = (-3.0f * t3 + 3.0f * t2 + 3.0f * tt + 1.0f) * s;
  b[3] = t3 * s;
}

__device__ __forceinline__ float waveReduce(float v) {
#pragma unroll
  for (int off = 32; off > 0; off >>= 1) v += __shfl_down(v, off);
  return v;
}

// Stage A: layer-1 decomposition for all 3 modalities (blocks (0..383, m))
// plus the fusion-weight computation (block (384, 0)). Every KAN output is a
// wave-level dot product over a CONTIGUOUS weight span against a dense
// zero-filled basis vector in LDS: coalesced, unconditional, independent
// loads -> latency pipelined.
__global__ __launch_bounds__(384) void stageA_kernel(
    const float* __restrict__ x, const float* __restrict__ y, const float* __restrict__ tg,
    const float* __restrict__ xbw, const float* __restrict__ xsw,
    const float* __restrict__ ybw, const float* __restrict__ ysw,
    const float* __restrict__ tbw, const float* __restrict__ tsw,
    const float* __restrict__ f1bw, const float* __restrict__ f1sw,
    const float* __restrict__ f2bw, const float* __restrict__ f2sw,
    float* __restrict__ A, float* __restrict__ Bt, float* __restrict__ wout)
{
  const int tid = threadIdx.x;
  const int lane = tid & 63, w = tid >> 6;
  const int i = blockIdx.x;
  const int m = blockIdx.y;

  if (i < NN) {
    // ---------------- kanAB path ----------------
    __shared__ float bas[HH * 8];   // dense basis, bas[d*8+k]
    __shared__ float sil[HH];
    const float* q  = (m == 0) ? x   : ((m == 1) ? y   : tg);
    const float* bw = (m == 0) ? xbw : ((m == 1) ? ybw : tbw);
    const float* sw = (m == 0) ? xsw : ((m == 1) ? ysw : tsw);

    if (tid < HH * 8) bas[tid] = 0.0f;
    __syncthreads();
    if (tid < HH) {
      float b[4]; float s; int kb;
      featEval(q[i * HH + tid], s, kb, b);
      sil[tid] = s;
#pragma unroll
      for (int r = 0; r < 4; ++r) {
        const int k = kb + r;
        if ((unsigned)k < 8u) bas[tid * 8 + k] = b[r];
      }
    }
    __syncthreads();

    // 100 outputs (o<50: A-half, cols 0..31; o>=50: B-half, cols 32..63),
    // wave w handles o = w, w+6, ...
    for (int o = w; o < 2 * MM; o += 6) {
      const int half = (o >= MM) ? 1 : 0;
      const int oo = o - half * MM;
      const int cb = half * HH;
      const float* sp = sw + ((size_t)(oo * 2 * HH + cb) << 3);  // 256 floats
      float acc = 0.0f;
#pragma unroll
      for (int r = 0; r < 4; ++r)
        acc = fmaf(sp[lane + 64 * r], bas[lane + 64 * r], acc);
      if (lane < HH)
        acc = fmaf(bw[oo * 2 * HH + cb + lane], sil[lane], acc);
      acc = waveReduce(acc);
      if (lane == 0) {
        if (half == 0) A[((size_t)m * NN + i) * MM + oo] = acc;
        else           Bt[((size_t)m * MM + oo) * NN + i] = acc;
      }
    }
    return;
  }

  // ---------------- fusion path (block (384,0) only) ----------------
  if (m != 0) return;
  {
    __shared__ float4 part4[3][8][16];
    __shared__ float sil96[96];
    __shared__ float bas768[96 * 8];
    __shared__ float z1[MM];
    __shared__ float sil2[MM];
    __shared__ float bas400[MM * 8];
    __shared__ float s3[3];

    // phase A: column means (float4-vectorized, 16-way split)
    {
      const int mm = tid >> 7;
      const int sub = tid & 127;
      const int q4 = sub >> 4;
      const int prt = sub & 15;
      const float* src = (mm == 0) ? x : ((mm == 1) ? y : tg);
      const float4* s4 = (const float4*)src;
      float4 a = make_float4(0.f, 0.f, 0.f, 0.f);
      for (int r = prt; r < NN; r += 16) {
        const float4 v = s4[r * 8 + q4];
        a.x += v.x; a.y += v.y; a.z += v.z; a.w += v.w;
      }
      part4[mm][q4][prt] = a;
    }
    for (int idx = tid; idx < 96 * 8; idx += 384) bas768[idx] = 0.0f;
    for (int idx = tid; idx < MM * 8; idx += 384) bas400[idx] = 0.0f;
    __syncthreads();

    // phase B: finish means, build sil96 + dense basis bas768
    if (tid < 96) {
      const int mm = tid >> 5, col = tid & 31;
      const int q4 = col >> 2, comp = col & 3;
      const float* pp = (const float*)&part4[mm][q4][0];
      float v = 0.0f;
#pragma unroll
      for (int prt = 0; prt < 16; ++prt) v += pp[prt * 4 + comp];
      const float fv = v * (1.0f / NN);
      float b[4]; float s; int kb;
      featEval(fv, s, kb, b);
      sil96[tid] = s;
#pragma unroll
      for (int r = 0; r < 4; ++r) {
        const int k = kb + r;
        if ((unsigned)k < 8u) bas768[tid * 8 + k] = b[r];
      }
    }
    __syncthreads();

    // layer 1: 50 outputs, wave-per-output contiguous-span dot
    for (int o = w; o < MM; o += 6) {
      const float* sp = f1sw + (size_t)o * (96 * 8);
      float acc = 0.0f;
#pragma unroll
      for (int r = 0; r < 12; ++r)
        acc = fmaf(sp[lane + 64 * r], bas768[lane + 64 * r], acc);
#pragma unroll
      for (int r = 0; r < 2; ++r) {
        const int e = lane + 64 * r;
        if (e < 96) acc = fmaf(f1bw[o * 96 + e], sil96[e], acc);
      }
      acc = waveReduce(acc);
      if (lane == 0) z1[o] = acc;
    }
    __syncthreads();

    // hidden activation features
    if (tid < MM) {
      float b[4]; float s; int kb;
      featEval(z1[tid], s, kb, b);
      sil2[tid] = s;
#pragma unroll
      for (int r = 0; r < 4; ++r) {
        const int k = kb + r;
        if ((unsigned)k < 8u) bas400[tid * 8 + k] = b[r];
      }
    }
    __syncthreads();

    // layer 2: 3 outputs, one wave each
    if (w < 3) {
      const float* sp = f2sw + (size_t)w * (MM * 8);
      float acc = 0.0f;
#pragma unroll
      for (int r = 0; r < 7; ++r) {
        const int e = lane + 64 * r;
        if (e < MM * 8) acc = fmaf(sp[e], bas400[e], acc);
      }
      if (lane < MM) acc = fmaf(f2bw[w * MM + lane], sil2[lane], acc);
      acc = waveReduce(acc);
      if (lane == 0) s3[w] = acc;
    }
    __syncthreads();

    if (tid == 0) {
      const float mx = fmaxf(s3[0], fmaxf(s3[1], s3[2]));
      const float e0 = __expf(s3[0] - mx), e1 = __expf(s3[1] - mx), e2 = __expf(s3[2] - mx);
      const float inv = fastRcp(e0 + e1 + e2);
      wout[0] = e0 * inv; wout[1] = e1 * inv; wout[2] = e2 * inv;
    }
  }
}

// Per-modality layer-2 KAN over all pairs: grid (384 rows, 3 modalities),
// 384 threads (one per column j). Sp[m][i][j] = kanLayer2_m(A_m[i]+B_m[j]).
// The spline is evaluated as a piecewise cubic via precomputed per-cell
// Horner coefficients (cells 1..11 real, 0 and 12 zero sentinels so the
// clamped cell index makes out-of-domain inputs evaluate to exactly 0).
__global__ __launch_bounds__(384) void score_kernel(
    const float* __restrict__ A, const float* __restrict__ Bt,
    const float* __restrict__ x2bw, const float* __restrict__ y2bw, const float* __restrict__ t2bw,
    const float* __restrict__ x2sw, const float* __restrict__ y2sw, const float* __restrict__ t2sw,
    float* __restrict__ Sp)
{
  __shared__ float sA[MM];
  __shared__ float sBW[MM];
  __shared__ float pad[MM][14];     // spline weights zero-padded +3 each side
  __shared__ float4 coef[MM][13];   // per-cell cubic coeffs (a0,a1,a2,a3)
  const int tid = threadIdx.x;
  const int i = blockIdx.x;
  const int m = blockIdx.y;
  const float* bsrc = (m == 0) ? x2bw : ((m == 1) ? y2bw : t2bw);
  const float* ssrc = (m == 0) ? x2sw : ((m == 1) ? y2sw : t2sw);

  for (int idx = tid; idx < MM * 6; idx += 384) {
    const int kk = idx / 6, r = idx - kk * 6;
    pad[kk][(r < 3) ? r : (r + 8)] = 0.0f;
  }
  for (int idx = tid; idx < MM * 8; idx += 384) {
    pad[idx >> 3][3 + (idx & 7)] = ssrc[idx];
  }
  if (tid < MM) {
    sA[tid]  = A[((size_t)m * NN + i) * MM + tid];
    sBW[tid] = bsrc[tid];
  }
  __syncthreads();

  // fold spline weights through the cardinal-basis matrix -> cubic coeffs
  for (int idx = tid; idx < MM * 11; idx += 384) {
    const int k = idx / 11, cm1 = idx - k * 11;   // cell-1: 0..10
    const float* bp = &pad[k][cm1];
    const float p0 = bp[0], p1 = bp[1], p2 = bp[2], p3 = bp[3];
    const float a0 = (p0 + 4.0f * p1 + p2) * (1.0f / 6.0f);
    const float a1 = (p2 - p0) * 0.5f;
    const float a2 = (p0 - 2.0f * p1 + p2) * 0.5f;
    const float a3 = (p3 - p0) * (1.0f / 6.0f) + (p1 - p2) * 0.5f;
    coef[k][cm1 + 1] = make_float4(a0, a1, a2, a3);
  }
  if (tid < MM * 2) {
    coef[tid >> 1][(tid & 1) * 12] = make_float4(0.f, 0.f, 0.f, 0.f);
  }
  __syncthreads();

  const float* BtBase = Bt + (size_t)m * MM * NN + tid;
  float acc0 = 0.0f, acc1 = 0.0f;
  for (int k = 0; k < MM; k += 2) {
    const float z0 = sA[k]     + BtBase[(size_t)k * NN];
    const float z1 = sA[k + 1] + BtBase[(size_t)(k + 1) * NN];
    {
      const float u = fmaf(z0, 2.5f, 2.5f);
      const float fu = floorf(u);
      const float t = u - fu;
      const int cc = (int)(fminf(fmaxf(fu, -4.0f), 8.0f)) + 4;
      const float4 C = coef[k][cc];
      acc0 += fmaf(t, fmaf(t, fmaf(t, C.w, C.z), C.y), C.x);
      const float sg = fastRcp(1.0f + __expf(-z0));
      acc0 = fmaf(z0 * sg, sBW[k], acc0);
    }
    {
      const float u = fmaf(z1, 2.5f, 2.5f);
      const float fu = floorf(u);
      const float t = u - fu;
      const int cc = (int)(fminf(fmaxf(fu, -4.0f), 8.0f)) + 4;
      const float4 C = coef[k + 1][cc];
      acc1 += fmaf(t, fmaf(t, fmaf(t, C.w, C.z), C.y), C.x);
      const float sg = fastRcp(1.0f + __expf(-z1));
      acc1 = fmaf(z1 * sg, sBW[k + 1], acc1);
    }
  }
  Sp[((size_t)m * NN + i) * NN + tid] = acc0 + acc1;
}

// Row kernel: weighted fuse of 3 score planes + bias, row softmax, @target,
// two final 32->32 KAN layers with relu. One block per row.
__global__ __launch_bounds__(384) void row_kernel(
    const float* __restrict__ Sp, const float* __restrict__ wv, const float* __restrict__ bias,
    const float* __restrict__ tg,
    const float* __restrict__ l1bw, const float* __restrict__ l1sw,
    const float* __restrict__ l2bw, const float* __restrict__ l2sw,
    float* __restrict__ out)
{
  __shared__ float p[NN];
  __shared__ float redm[8], reds[8];
  __shared__ float part[12][HH];
  __shared__ float ta[HH];
  __shared__ float fsil[HH];
  __shared__ int   fkb[HH];
  __shared__ float fbs[HH][4];
  __shared__ float y1v[HH];
  const int tid = threadIdx.x;
  const int i = blockIdx.x;

  float stot = bias[0];
  stot = fmaf(wv[0], Sp[(size_t)i * NN + tid], stot);
  stot = fmaf(wv[1], Sp[((size_t)NN + i) * NN + tid], stot);
  stot = fmaf(wv[2], Sp[((size_t)2 * NN + i) * NN + tid], stot);

  // ---- row softmax ----
  const int lane = tid & 63, wid = tid >> 6;
  float v = stot;
#pragma unroll
  for (int off = 32; off > 0; off >>= 1) v = fmaxf(v, __shfl_down(v, off));
  if (lane == 0) redm[wid] = v;
  __syncthreads();
  float mx = redm[0];
#pragma unroll
  for (int w = 1; w < 6; ++w) mx = fmaxf(mx, redm[w]);
  const float e = __expf(stot - mx);
  p[tid] = e;
  float sv = e;
#pragma unroll
  for (int off = 32; off > 0; off >>= 1) sv += __shfl_down(sv, off);
  if (lane == 0) reds[wid] = sv;
  __syncthreads();
  const float ssum = reds[0] + reds[1] + reds[2] + reds[3] + reds[4] + reds[5];
  const float inv = 1.0f / ssum;

  // ---- target_att row ----
  const int d = tid & 31, g = tid >> 5;
  float acc2 = 0.0f;
  for (int s2 = 0; s2 < 32; ++s2) {
    const int j = g * 32 + s2;
    acc2 = fmaf(p[j], tg[j * HH + d], acc2);
  }
  part[g][d] = acc2;
  __syncthreads();
  if (tid < HH) {
    float a = 0.0f;
#pragma unroll
    for (int gg = 0; gg < 12; ++gg) a += part[gg][tid];
    ta[tid] = a * inv;
  }
  __syncthreads();

  // ---- final KAN layer 1 (32 -> 32, relu) ----
  if (tid < HH) {
    float b[4]; float s; int k;
    featEval(ta[tid], s, k, b);
    fsil[tid] = s; fkb[tid] = k;
    fbs[tid][0] = b[0]; fbs[tid][1] = b[1]; fbs[tid][2] = b[2]; fbs[tid][3] = b[3];
  }
  __syncthreads();
  if (tid < HH) {
    float acc = 0.0f;
    for (int dd = 0; dd < HH; ++dd) {
      acc = fmaf(fsil[dd], l1bw[tid * HH + dd], acc);
      const float* swrow = l1sw + ((size_t)(tid * HH + dd) << 3);
      const int kbd = fkb[dd];
#pragma unroll
      for (int r = 0; r < 4; ++r) {
        const int k = kbd + r;
        if ((unsigned)k < 8u) acc = fmaf(fbs[dd][r], swrow[k], acc);
      }
    }
    y1v[tid] = fmaxf(acc, 0.0f);
  }
  __syncthreads();

  // ---- final KAN layer 2 (32 -> 32, relu) ----
  if (tid < HH) {
    float b[4]; float s; int k;
    featEval(y1v[tid], s, k, b);
    fsil[tid] = s; fkb[tid] = k;
    fbs[tid][0] = b[0]; fbs[tid][1] = b[1]; fbs[tid][2] = b[2]; fbs[tid][3] = b[3];
  }
  __syncthreads();
  if (tid < HH) {
    float acc = 0.0f;
    for (int dd = 0; dd < HH; ++dd) {
      acc = fmaf(fsil[dd], l2bw[tid * HH + dd], acc);
      const float* swrow = l2sw + ((size_t)(tid * HH + dd) << 3);
      const int kbd = fkb[dd];
#pragma unroll
      for (int r = 0; r < 4; ++r) {
        const int k = kbd + r;
        if ((unsigned)k < 8u) acc = fmaf(fbs[dd][r], swrow[k], acc);
      }
    }
    out[i * HH + tid] = fmaxf(acc, 0.0f);
  }
}

extern "C" void kernel_launch(void* const* d_in, const int* in_sizes, int n_in,
                              void* d_out, int out_size, void* d_ws, size_t ws_size,
                              hipStream_t stream)
{
  const float* x    = (const float*)d_in[0];
  const float* y    = (const float*)d_in[1];
  const float* tg   = (const float*)d_in[2];
  const float* bias = (const float*)d_in[3];
  const float* x1bw = (const float*)d_in[4];
  const float* x1sw = (const float*)d_in[5];
  const float* x2bw = (const float*)d_in[6];
  const float* x2sw = (const float*)d_in[7];
  const float* y1bw = (const float*)d_in[8];
  const float* y1sw = (const float*)d_in[9];
  const float* y2bw = (const float*)d_in[10];
  const float* y2sw = (const float*)d_in[11];
  const float* t1bw = (const float*)d_in[12];
  const float* t1sw = (const float*)d_in[13];
  const float* t2bw = (const float*)d_in[14];
  const float* t2sw = (const float*)d_in[15];
  const float* f1bw = (const float*)d_in[16];
  const float* f1sw = (const float*)d_in[17];
  const float* f2bw = (const float*)d_in[18];
  const float* f2sw = (const float*)d_in[19];
  const float* l1bw = (const float*)d_in[20];
  const float* l1sw = (const float*)d_in[21];
  const float* l2bw = (const float*)d_in[22];
  const float* l2sw = (const float*)d_in[23];
  float* out = (float*)d_out;

  float* ws = (float*)d_ws;
  float* A  = ws;                          // [3][384][50]
  float* Bt = ws + 3 * NN * MM;            // [3][50][384]
  float* Sp = ws + 6 * NN * MM;            // [3][384][384]
  float* wv = Sp + 3 * NN * NN;            // [3]

  stageA_kernel<<<dim3(NN + 1, 3), 384, 0, stream>>>(
      x, y, tg, x1bw, x1sw, y1bw, y1sw, t1bw, t1sw,
      f1bw, f1sw, f2bw, f2sw, A, Bt, wv);
  score_kernel<<<dim3(NN, 3), 384, 0, stream>>>(A, Bt, x2bw, y2bw, t2bw,
                                                x2sw, y2sw, t2sw, Sp);
  row_kernel<<<NN, 384, 0, stream>>>(Sp, wv, bias, tg, l1bw, l1sw, l2bw, l2sw, out);
}

// Round 5
// 59.766 us; speedup vs baseline: 3.3948x; 1.0834x over previous
//
#include <hip/hip_runtime.h>

#define NN 384
#define HH 32
#define MM 50

__device__ __forceinline__ float fastRcp(float x) { return __builtin_amdgcn_rcpf(x); }

// Closed-form cardinal cubic B-spline features for the efficient-kan uniform
// grid: GRID_SIZE=5, SPLINE_ORDER=3, h=0.4, knots g[c]=(c-3)*h-1, c=0..11.
// Valid domain x in [-2.2, 2.2); outside -> zero basis (s=0), kb=100 sentinel.
__device__ __forceinline__ void featEval(float x, float& sil, int& kb, float b[4]) {
  sil = x * fastRcp(1.0f + __expf(-x));           // silu
  const float u  = (x + 1.0f) * 2.5f;
  const float fu = floorf(u);
  const bool valid = (fu >= -3.0f) && (fu <= 7.0f);
  const float s = valid ? (1.0f / 6.0f) : 0.0f;
  kb = valid ? (int)fu : 100;
  const float tt = u - fu;
  const float t2 = tt * tt, t3 = t2 * tt, omt = 1.0f - tt;
  b[0] = omt * omt * omt * s;
  b[1] = (3.0f * t3 - 6.0f * t2 + 4.0f) * s;
  b[2] = (-3.0f * t3 + 3.0f * t2 + 3.0f * tt + 1.0f) * s;
  b[3] = t3 * s;
}

__device__ __forceinline__ float waveReduce(float v) {
#pragma unroll
  for (int off = 32; off > 0; off >>= 1) v += __shfl_down(v, off);
  return v;
}

__device__ __forceinline__ float dot4(float4 a, float4 b) {
  float r = a.x * b.x;
  r = fmaf(a.y, b.y, r);
  r = fmaf(a.z, b.z, r);
  r = fmaf(a.w, b.w, r);
  return r;
}

// Stage A: layer-1 decomposition for all 3 modalities. Grid (385, 3, 2):
// blocks (i<384, m, half) compute 50 outputs of the A-half (half=0, weight
// cols 0..31) or B-half (half=1, cols 32..63) for row i of modality m; block
// (384, 0, 0) computes the fusion weights. Every KAN output is a wave-level
// float4 dot product over a CONTIGUOUS weight span against a dense
// zero-filled basis vector in LDS: one global dwordx4 + one ds_read_b128 +
// 4 FMA + shuffle reduce per output per lane.
__global__ __launch_bounds__(384) void stageA_kernel(
    const float* __restrict__ x, const float* __restrict__ y, const float* __restrict__ tg,
    const float* __restrict__ xbw, const float* __restrict__ xsw,
    const float* __restrict__ ybw, const float* __restrict__ ysw,
    const float* __restrict__ tbw, const float* __restrict__ tsw,
    const float* __restrict__ f1bw, const float* __restrict__ f1sw,
    const float* __restrict__ f2bw, const float* __restrict__ f2sw,
    float* __restrict__ A, float* __restrict__ Bt, float* __restrict__ wout)
{
  const int tid = threadIdx.x;
  const int lane = tid & 63, w = tid >> 6;
  const int i = blockIdx.x;
  const int m = blockIdx.y;
  const int half = blockIdx.z;

  if (i < NN) {
    // ---------------- kanAB path ----------------
    __shared__ float bas[HH * 8];   // dense basis, bas[d*8+k]
    __shared__ float sil[HH];
    const float* q  = (m == 0) ? x   : ((m == 1) ? y   : tg);
    const float* bw = (m == 0) ? xbw : ((m == 1) ? ybw : tbw);
    const float* sw = (m == 0) ? xsw : ((m == 1) ? ysw : tsw);
    const int cb = half * HH;       // weight column base for this half

    if (tid < HH * 8) bas[tid] = 0.0f;
    __syncthreads();
    if (tid < HH) {
      float b[4]; float s; int kb;
      featEval(q[i * HH + tid], s, kb, b);   // features are q[i] for BOTH halves
      sil[tid] = s;
#pragma unroll
      for (int r = 0; r < 4; ++r) {
        const int k = kb + r;
        if ((unsigned)k < 8u) bas[tid * 8 + k] = b[r];
      }
    }
    __syncthreads();

    const float4* bas4 = (const float4*)bas;
    const float4 bb = bas4[lane];
    for (int o = w; o < MM; o += 6) {
      const float4* sp4 = (const float4*)(sw + ((size_t)(o * 2 * HH + cb) << 3));
      float acc = dot4(sp4[lane], bb);
      if (lane < HH)
        acc = fmaf(bw[o * 2 * HH + cb + lane], sil[lane], acc);
      acc = waveReduce(acc);
      if (lane == 0) {
        if (half == 0) A[((size_t)m * NN + i) * MM + o] = acc;
        else           Bt[((size_t)m * MM + o) * NN + i] = acc;
      }
    }
    return;
  }

  // ---------------- fusion path (block (384,0,0) only) ----------------
  if (m != 0 || half != 0) return;
  {
    __shared__ float4 part4[3][8][16];
    __shared__ float sil96[96];
    __shared__ float bas768[96 * 8];
    __shared__ float z1[MM];
    __shared__ float sil2[MM];
    __shared__ float bas400[MM * 8];
    __shared__ float s3[3];

    // phase A: column means (float4-vectorized, 16-way split)
    {
      const int mm = tid >> 7;
      const int sub = tid & 127;
      const int q4 = sub >> 4;
      const int prt = sub & 15;
      const float* src = (mm == 0) ? x : ((mm == 1) ? y : tg);
      const float4* s4 = (const float4*)src;
      float4 a = make_float4(0.f, 0.f, 0.f, 0.f);
      for (int r = prt; r < NN; r += 16) {
        const float4 v = s4[r * 8 + q4];
        a.x += v.x; a.y += v.y; a.z += v.z; a.w += v.w;
      }
      part4[mm][q4][prt] = a;
    }
    for (int idx = tid; idx < 96 * 8; idx += 384) bas768[idx] = 0.0f;
    for (int idx = tid; idx < MM * 8; idx += 384) bas400[idx] = 0.0f;
    __syncthreads();

    // phase B: finish means, build sil96 + dense basis bas768
    if (tid < 96) {
      const int mm = tid >> 5, col = tid & 31;
      const int q4 = col >> 2, comp = col & 3;
      const float* pp = (const float*)&part4[mm][q4][0];
      float v = 0.0f;
#pragma unroll
      for (int prt = 0; prt < 16; ++prt) v += pp[prt * 4 + comp];
      const float fv = v * (1.0f / NN);
      float b[4]; float s; int kb;
      featEval(fv, s, kb, b);
      sil96[tid] = s;
#pragma unroll
      for (int r = 0; r < 4; ++r) {
        const int k = kb + r;
        if ((unsigned)k < 8u) bas768[tid * 8 + k] = b[r];
      }
    }
    __syncthreads();

    // layer 1: 50 outputs, wave-per-output contiguous float4 dot
    {
      const float4* bas4 = (const float4*)bas768;
      for (int o = w; o < MM; o += 6) {
        const float4* sp4 = (const float4*)(f1sw + (size_t)o * (96 * 8));
        float acc = 0.0f;
#pragma unroll
        for (int r = 0; r < 3; ++r)
          acc += dot4(sp4[lane + 64 * r], bas4[lane + 64 * r]);
#pragma unroll
        for (int r = 0; r < 2; ++r) {
          const int e = lane + 64 * r;
          if (e < 96) acc = fmaf(f1bw[o * 96 + e], sil96[e], acc);
        }
        acc = waveReduce(acc);
        if (lane == 0) z1[o] = acc;
      }
    }
    __syncthreads();

    // hidden activation features
    if (tid < MM) {
      float b[4]; float s; int kb;
      featEval(z1[tid], s, kb, b);
      sil2[tid] = s;
#pragma unroll
      for (int r = 0; r < 4; ++r) {
        const int k = kb + r;
        if ((unsigned)k < 8u) bas400[tid * 8 + k] = b[r];
      }
    }
    __syncthreads();

    // layer 2: 3 outputs, one wave each
    if (w < 3) {
      const float4* bas4 = (const float4*)bas400;
      const float4* sp4 = (const float4*)(f2sw + (size_t)w * (MM * 8));
      float acc = 0.0f;
#pragma unroll
      for (int r = 0; r < 2; ++r) {
        const int f = lane + 64 * r;
        if (f < MM * 2) acc += dot4(sp4[f], bas4[f]);
      }
      if (lane < MM) acc = fmaf(f2bw[w * MM + lane], sil2[lane], acc);
      acc = waveReduce(acc);
      if (lane == 0) s3[w] = acc;
    }
    __syncthreads();

    if (tid == 0) {
      const float mx = fmaxf(s3[0], fmaxf(s3[1], s3[2]));
      const float e0 = __expf(s3[0] - mx), e1 = __expf(s3[1] - mx), e2 = __expf(s3[2] - mx);
      const float inv = fastRcp(e0 + e1 + e2);
      wout[0] = e0 * inv; wout[1] = e1 * inv; wout[2] = e2 * inv;
    }
  }
}

// Stage B: one block per attention row i. Thread j computes the fused score
// s[i,j] = bias + sum_m wv_m * kanLayer2_m(A_m[i]+B_m[j]) via per-cell Horner
// coefficient tables in LDS (cells 1..11 real, 0/12 zero sentinels); block
// softmax; @target; two final 32->32 KAN layers via float4 wave-dots.
__global__ __launch_bounds__(384) void stageB_kernel(
    const float* __restrict__ A, const float* __restrict__ Bt,
    const float* __restrict__ x2bw, const float* __restrict__ y2bw, const float* __restrict__ t2bw,
    const float* __restrict__ x2sw, const float* __restrict__ y2sw, const float* __restrict__ t2sw,
    const float* __restrict__ wv, const float* __restrict__ bias,
    const float* __restrict__ tg,
    const float* __restrict__ l1bw, const float* __restrict__ l1sw,
    const float* __restrict__ l2bw, const float* __restrict__ l2sw,
    float* __restrict__ out)
{
  __shared__ float sA[3][MM];
  __shared__ float sBW[3][MM];
  __shared__ float pad[3][MM][14];
  __shared__ float4 coef[3][MM][13];
  __shared__ float swvb[4];
  __shared__ float p[NN];
  __shared__ float redm[6], reds[6];
  __shared__ float part[12][HH];
  __shared__ float ta[HH];
  __shared__ float basF[HH * 8];
  __shared__ float silF[HH];
  __shared__ float y1v[HH];

  const int tid = threadIdx.x;
  const int lane = tid & 63, w = tid >> 6;
  const int i = blockIdx.x;

  // ---- build per-modality layer-2 tables ----
  for (int idx = tid; idx < 3 * MM * 6; idx += 384) {
    const int m = idx / (MM * 6);
    const int rem = idx - m * (MM * 6);
    const int kk = rem / 6, r = rem - kk * 6;
    pad[m][kk][(r < 3) ? r : (r + 8)] = 0.0f;
  }
  for (int idx = tid; idx < 3 * MM * 8; idx += 384) {
    const int m = idx / (MM * 8);
    const int rem = idx - m * (MM * 8);
    const float* ssrc = (m == 0) ? x2sw : ((m == 1) ? y2sw : t2sw);
    pad[m][rem >> 3][3 + (rem & 7)] = ssrc[rem];
  }
  if (tid < 3 * MM) {
    const int m = tid / MM, o = tid - m * MM;
    sA[m][o] = A[((size_t)m * NN + i) * MM + o];
    const float* bsrc = (m == 0) ? x2bw : ((m == 1) ? y2bw : t2bw);
    sBW[m][o] = bsrc[o];
  }
  if (tid == 0) { swvb[0] = wv[0]; swvb[1] = wv[1]; swvb[2] = wv[2]; swvb[3] = bias[0]; }
  __syncthreads();

  for (int idx = tid; idx < 3 * MM * 11; idx += 384) {
    const int m = idx / (MM * 11);
    const int rem = idx - m * (MM * 11);
    const int k = rem / 11, cm1 = rem - k * 11;
    const float* bp = &pad[m][k][cm1];
    const float p0 = bp[0], p1 = bp[1], p2 = bp[2], p3 = bp[3];
    const float a0 = (p0 + 4.0f * p1 + p2) * (1.0f / 6.0f);
    const float a1 = (p2 - p0) * 0.5f;
    const float a2 = (p0 - 2.0f * p1 + p2) * 0.5f;
    const float a3 = (p3 - p0) * (1.0f / 6.0f) + (p1 - p2) * 0.5f;
    coef[m][k][cm1 + 1] = make_float4(a0, a1, a2, a3);
  }
  if (tid < 3 * MM * 2) {
    const int m = tid / (MM * 2);
    const int rem = tid - m * (MM * 2);
    coef[m][rem >> 1][(rem & 1) * 12] = make_float4(0.f, 0.f, 0.f, 0.f);
  }
  __syncthreads();

  // ---- fused pair score ----
  float stot = swvb[3];
#pragma unroll
  for (int m = 0; m < 3; ++m) {
    const float* BtB = Bt + (size_t)m * MM * NN + tid;
    float acc0 = 0.0f, acc1 = 0.0f;
    for (int k = 0; k < MM; k += 2) {
      const float z0 = sA[m][k]     + BtB[(size_t)k * NN];
      const float z1 = sA[m][k + 1] + BtB[(size_t)(k + 1) * NN];
      {
        const float u = fmaf(z0, 2.5f, 2.5f);
        const float fu = floorf(u);
        const float t = u - fu;
        const int cc = (int)(fminf(fmaxf(fu, -4.0f), 8.0f)) + 4;
        const float4 C = coef[m][k][cc];
        acc0 += fmaf(t, fmaf(t, fmaf(t, C.w, C.z), C.y), C.x);
        const float sg = fastRcp(1.0f + __expf(-z0));
        acc0 = fmaf(z0 * sg, sBW[m][k], acc0);
      }
      {
        const float u = fmaf(z1, 2.5f, 2.5f);
        const float fu = floorf(u);
        const float t = u - fu;
        const int cc = (int)(fminf(fmaxf(fu, -4.0f), 8.0f)) + 4;
        const float4 C = coef[m][k + 1][cc];
        acc1 += fmaf(t, fmaf(t, fmaf(t, C.w, C.z), C.y), C.x);
        const float sg = fastRcp(1.0f + __expf(-z1));
        acc1 = fmaf(z1 * sg, sBW[m][k + 1], acc1);
      }
    }
    stot = fmaf(swvb[m], acc0 + acc1, stot);
  }

  // ---- row softmax ----
  float v = stot;
#pragma unroll
  for (int off = 32; off > 0; off >>= 1) v = fmaxf(v, __shfl_down(v, off));
  if (lane == 0) redm[w] = v;
  __syncthreads();
  float mx = redm[0];
#pragma unroll
  for (int ww = 1; ww < 6; ++ww) mx = fmaxf(mx, redm[ww]);
  const float e = __expf(stot - mx);
  p[tid] = e;
  float sv = e;
#pragma unroll
  for (int off = 32; off > 0; off >>= 1) sv += __shfl_down(sv, off);
  if (lane == 0) reds[w] = sv;
  __syncthreads();
  const float ssum = reds[0] + reds[1] + reds[2] + reds[3] + reds[4] + reds[5];
  const float inv = fastRcp(ssum);

  // ---- target_att row ----
  const int d = tid & 31, g = tid >> 5;
  float acc2 = 0.0f;
  for (int s2 = 0; s2 < 32; ++s2) {
    const int j = g * 32 + s2;
    acc2 = fmaf(p[j], tg[j * HH + d], acc2);
  }
  part[g][d] = acc2;
  if (tid < HH * 8) basF[tid] = 0.0f;
  __syncthreads();
  if (tid < HH) {
    float a = 0.0f;
#pragma unroll
    for (int gg = 0; gg < 12; ++gg) a += part[gg][tid];
    ta[tid] = a * inv;
  }
  __syncthreads();

  // ---- final KAN layer 1 (32 -> 32, relu) via float4 wave-dot ----
  if (tid < HH) {
    float b[4]; float s; int kb;
    featEval(ta[tid], s, kb, b);
    silF[tid] = s;
#pragma unroll
    for (int r = 0; r < 4; ++r) {
      const int k = kb + r;
      if ((unsigned)k < 8u) basF[tid * 8 + k] = b[r];
    }
  }
  __syncthreads();
  {
    const float4 bb = ((const float4*)basF)[lane];
    for (int o = w; o < HH; o += 6) {
      const float4* sp4 = (const float4*)(l1sw + ((size_t)o << 8));
      float acc = dot4(sp4[lane], bb);
      if (lane < HH) acc = fmaf(l1bw[o * HH + lane], silF[lane], acc);
      acc = waveReduce(acc);
      if (lane == 0) y1v[o] = fmaxf(acc, 0.0f);
    }
  }
  __syncthreads();
  if (tid < HH * 8) basF[tid] = 0.0f;
  __syncthreads();
  if (tid < HH) {
    float b[4]; float s; int kb;
    featEval(y1v[tid], s, kb, b);
    silF[tid] = s;
#pragma unroll
    for (int r = 0; r < 4; ++r) {
      const int k = kb + r;
      if ((unsigned)k < 8u) basF[tid * 8 + k] = b[r];
    }
  }
  __syncthreads();
  // ---- final KAN layer 2 (32 -> 32, relu) ----
  {
    const float4 bb = ((const float4*)basF)[lane];
    for (int o = w; o < HH; o += 6) {
      const float4* sp4 = (const float4*)(l2sw + ((size_t)o << 8));
      float acc = dot4(sp4[lane], bb);
      if (lane < HH) acc = fmaf(l2bw[o * HH + lane], silF[lane], acc);
      acc = waveReduce(acc);
      if (lane == 0) out[i * HH + o] = fmaxf(acc, 0.0f);
    }
  }
}

extern "C" void kernel_launch(void* const* d_in, const int* in_sizes, int n_in,
                              void* d_out, int out_size, void* d_ws, size_t ws_size,
                              hipStream_t stream)
{
  const float* x    = (const float*)d_in[0];
  const float* y    = (const float*)d_in[1];
  const float* tg   = (const float*)d_in[2];
  const float* bias = (const float*)d_in[3];
  const float* x1bw = (const float*)d_in[4];
  const float* x1sw = (const float*)d_in[5];
  const float* x2bw = (const float*)d_in[6];
  const float* x2sw = (const float*)d_in[7];
  const float* y1bw = (const float*)d_in[8];
  const float* y1sw = (const float*)d_in[9];
  const float* y2bw = (const float*)d_in[10];
  const float* y2sw = (const float*)d_in[11];
  const float* t1bw = (const float*)d_in[12];
  const float* t1sw = (const float*)d_in[13];
  const float* t2bw = (const float*)d_in[14];
  const float* t2sw = (const float*)d_in[15];
  const float* f1bw = (const float*)d_in[16];
  const float* f1sw = (const float*)d_in[17];
  const float* f2bw = (const float*)d_in[18];
  const float* f2sw = (const float*)d_in[19];
  const float* l1bw = (const float*)d_in[20];
  const float* l1sw = (const float*)d_in[21];
  const float* l2bw = (const float*)d_in[22];
  const float* l2sw = (const float*)d_in[23];
  float* out = (float*)d_out;

  float* ws = (float*)d_ws;
  float* A  = ws;                          // [3][384][50]
  float* Bt = ws + 3 * NN * MM;            // [3][50][384]
  float* wv = ws + 6 * NN * MM;            // [3]

  stageA_kernel<<<dim3(NN + 1, 3, 2), 384, 0, stream>>>(
      x, y, tg, x1bw, x1sw, y1bw, y1sw, t1bw, t1sw,
      f1bw, f1sw, f2bw, f2sw, A, Bt, wv);
  stageB_kernel<<<NN, 384, 0, stream>>>(A, Bt, x2bw, y2bw, t2bw, x2sw, y2sw, t2sw,
                                        wv, bias, tg, l1bw, l1sw, l2bw, l2sw, out);
}

// Round 6
// 48.624 us; speedup vs baseline: 4.1727x; 1.2292x over previous
//
#include <hip/hip_runtime.h>

#define NN 384
#define HH 32
#define MM 50

__device__ __forceinline__ float fastRcp(float x) { return __builtin_amdgcn_rcpf(x); }

// Closed-form cardinal cubic B-spline features for the efficient-kan uniform
// grid: GRID_SIZE=5, SPLINE_ORDER=3, h=0.4, knots g[c]=(c-3)*h-1, c=0..11.
// Valid domain x in [-2.2, 2.2); outside -> zero basis (s=0), kb=100 sentinel.
__device__ __forceinline__ void featEval(float x, float& sil, int& kb, float b[4]) {
  sil = x * fastRcp(1.0f + __expf(-x));           // silu
  const float u  = (x + 1.0f) * 2.5f;
  const float fu = floorf(u);
  const bool valid = (fu >= -3.0f) && (fu <= 7.0f);
  const float s = valid ? (1.0f / 6.0f) : 0.0f;
  kb = valid ? (int)fu : 100;
  const float tt = u - fu;
  const float t2 = tt * tt, t3 = t2 * tt, omt = 1.0f - tt;
  b[0] = omt * omt * omt * s;
  b[1] = (3.0f * t3 - 6.0f * t2 + 4.0f) * s;
  b[2] = (-3.0f * t3 + 3.0f * t2 + 3.0f * tt + 1.0f) * s;
  b[3] = t3 * s;
}

__device__ __forceinline__ float waveReduce(float v) {
#pragma unroll
  for (int off = 32; off > 0; off >>= 1) v += __shfl_down(v, off);
  return v;
}

__device__ __forceinline__ float dot4(float4 a, float4 b) {
  float r = a.x * b.x;
  r = fmaf(a.y, b.y, r);
  r = fmaf(a.z, b.z, r);
  r = fmaf(a.w, b.w, r);
  return r;
}

// Stage A: layer-1 decomposition for all 3 modalities. Grid (385, 3, 2):
// blocks (i<384, m, half) compute 50 outputs of the A-half (half=0, weight
// cols 0..31) or B-half (half=1, cols 32..63) for row i of modality m; block
// (384, 0, 0) computes the fusion weights. Every KAN output is a wave-level
// float4 dot product over a CONTIGUOUS weight span against a dense
// zero-filled basis vector in LDS.
__global__ __launch_bounds__(384) void stageA_kernel(
    const float* __restrict__ x, const float* __restrict__ y, const float* __restrict__ tg,
    const float* __restrict__ xbw, const float* __restrict__ xsw,
    const float* __restrict__ ybw, const float* __restrict__ ysw,
    const float* __restrict__ tbw, const float* __restrict__ tsw,
    const float* __restrict__ f1bw, const float* __restrict__ f1sw,
    const float* __restrict__ f2bw, const float* __restrict__ f2sw,
    float* __restrict__ A, float* __restrict__ Bt, float* __restrict__ wout)
{
  const int tid = threadIdx.x;
  const int lane = tid & 63, w = tid >> 6;
  const int i = blockIdx.x;
  const int m = blockIdx.y;
  const int half = blockIdx.z;

  if (i < NN) {
    // ---------------- kanAB path ----------------
    __shared__ float bas[HH * 8];   // dense basis, bas[d*8+k]
    __shared__ float sil[HH];
    const float* q  = (m == 0) ? x   : ((m == 1) ? y   : tg);
    const float* bw = (m == 0) ? xbw : ((m == 1) ? ybw : tbw);
    const float* sw = (m == 0) ? xsw : ((m == 1) ? ysw : tsw);
    const int cb = half * HH;       // weight column base for this half

    if (tid < HH * 8) bas[tid] = 0.0f;
    __syncthreads();
    if (tid < HH) {
      float b[4]; float s; int kb;
      featEval(q[i * HH + tid], s, kb, b);   // features are q[i] for BOTH halves
      sil[tid] = s;
#pragma unroll
      for (int r = 0; r < 4; ++r) {
        const int k = kb + r;
        if ((unsigned)k < 8u) bas[tid * 8 + k] = b[r];
      }
    }
    __syncthreads();

    const float4* bas4 = (const float4*)bas;
    const float4 bb = bas4[lane];
    for (int o = w; o < MM; o += 6) {
      const float4* sp4 = (const float4*)(sw + ((size_t)(o * 2 * HH + cb) << 3));
      float acc = dot4(sp4[lane], bb);
      if (lane < HH)
        acc = fmaf(bw[o * 2 * HH + cb + lane], sil[lane], acc);
      acc = waveReduce(acc);
      if (lane == 0) {
        if (half == 0) A[((size_t)m * NN + i) * MM + o] = acc;
        else           Bt[((size_t)m * MM + o) * NN + i] = acc;
      }
    }
    return;
  }

  // ---------------- fusion path (block (384,0,0) only) ----------------
  if (m != 0 || half != 0) return;
  {
    __shared__ float4 part4[3][8][16];
    __shared__ float sil96[96];
    __shared__ float bas768[96 * 8];
    __shared__ float z1[MM];
    __shared__ float sil2[MM];
    __shared__ float bas400[MM * 8];
    __shared__ float s3[3];

    // phase A: column means (float4-vectorized, 16-way split)
    {
      const int mm = tid >> 7;
      const int sub = tid & 127;
      const int q4 = sub >> 4;
      const int prt = sub & 15;
      const float* src = (mm == 0) ? x : ((mm == 1) ? y : tg);
      const float4* s4 = (const float4*)src;
      float4 a = make_float4(0.f, 0.f, 0.f, 0.f);
      for (int r = prt; r < NN; r += 16) {
        const float4 v = s4[r * 8 + q4];
        a.x += v.x; a.y += v.y; a.z += v.z; a.w += v.w;
      }
      part4[mm][q4][prt] = a;
    }
    for (int idx = tid; idx < 96 * 8; idx += 384) bas768[idx] = 0.0f;
    for (int idx = tid; idx < MM * 8; idx += 384) bas400[idx] = 0.0f;
    __syncthreads();

    // phase B: finish means, build sil96 + dense basis bas768
    if (tid < 96) {
      const int mm = tid >> 5, col = tid & 31;
      const int q4 = col >> 2, comp = col & 3;
      const float* pp = (const float*)&part4[mm][q4][0];
      float v = 0.0f;
#pragma unroll
      for (int prt = 0; prt < 16; ++prt) v += pp[prt * 4 + comp];
      const float fv = v * (1.0f / NN);
      float b[4]; float s; int kb;
      featEval(fv, s, kb, b);
      sil96[tid] = s;
#pragma unroll
      for (int r = 0; r < 4; ++r) {
        const int k = kb + r;
        if ((unsigned)k < 8u) bas768[tid * 8 + k] = b[r];
      }
    }
    __syncthreads();

    // layer 1: 50 outputs, wave-per-output contiguous float4 dot
    {
      const float4* bas4 = (const float4*)bas768;
      for (int o = w; o < MM; o += 6) {
        const float4* sp4 = (const float4*)(f1sw + (size_t)o * (96 * 8));
        float acc = 0.0f;
#pragma unroll
        for (int r = 0; r < 3; ++r)
          acc += dot4(sp4[lane + 64 * r], bas4[lane + 64 * r]);
#pragma unroll
        for (int r = 0; r < 2; ++r) {
          const int e = lane + 64 * r;
          if (e < 96) acc = fmaf(f1bw[o * 96 + e], sil96[e], acc);
        }
        acc = waveReduce(acc);
        if (lane == 0) z1[o] = acc;
      }
    }
    __syncthreads();

    // hidden activation features
    if (tid < MM) {
      float b[4]; float s; int kb;
      featEval(z1[tid], s, kb, b);
      sil2[tid] = s;
#pragma unroll
      for (int r = 0; r < 4; ++r) {
        const int k = kb + r;
        if ((unsigned)k < 8u) bas400[tid * 8 + k] = b[r];
      }
    }
    __syncthreads();

    // layer 2: 3 outputs, one wave each
    if (w < 3) {
      const float4* bas4 = (const float4*)bas400;
      const float4* sp4 = (const float4*)(f2sw + (size_t)w * (MM * 8));
      float acc = 0.0f;
#pragma unroll
      for (int r = 0; r < 2; ++r) {
        const int f = lane + 64 * r;
        if (f < MM * 2) acc += dot4(sp4[f], bas4[f]);
      }
      if (lane < MM) acc = fmaf(f2bw[w * MM + lane], sil2[lane], acc);
      acc = waveReduce(acc);
      if (lane == 0) s3[w] = acc;
    }
    __syncthreads();

    if (tid == 0) {
      const float mx = fmaxf(s3[0], fmaxf(s3[1], s3[2]));
      const float e0 = __expf(s3[0] - mx), e1 = __expf(s3[1] - mx), e2 = __expf(s3[2] - mx);
      const float inv = fastRcp(e0 + e1 + e2);
      wout[0] = e0 * inv; wout[1] = e1 * inv; wout[2] = e2 * inv;
    }
  }
}

// Per-modality layer-2 KAN over all pairs: grid (384 rows, 3 modalities),
// 384 threads (one per column j). Sp[m][i][j] = kanLayer2_m(A_m[i]+B_m[j]).
// The spline is evaluated as a piecewise cubic via precomputed per-cell
// Horner coefficients (cells 1..11 real, 0 and 12 zero sentinels so the
// clamped cell index makes out-of-domain inputs evaluate to exactly 0).
__global__ __launch_bounds__(384) void score_kernel(
    const float* __restrict__ A, const float* __restrict__ Bt,
    const float* __restrict__ x2bw, const float* __restrict__ y2bw, const float* __restrict__ t2bw,
    const float* __restrict__ x2sw, const float* __restrict__ y2sw, const float* __restrict__ t2sw,
    float* __restrict__ Sp)
{
  __shared__ float sA[MM];
  __shared__ float sBW[MM];
  __shared__ float pad[MM][14];     // spline weights zero-padded +3 each side
  __shared__ float4 coef[MM][13];   // per-cell cubic coeffs (a0,a1,a2,a3)
  const int tid = threadIdx.x;
  const int i = blockIdx.x;
  const int m = blockIdx.y;
  const float* bsrc = (m == 0) ? x2bw : ((m == 1) ? y2bw : t2bw);
  const float* ssrc = (m == 0) ? x2sw : ((m == 1) ? y2sw : t2sw);

  for (int idx = tid; idx < MM * 6; idx += 384) {
    const int kk = idx / 6, r = idx - kk * 6;
    pad[kk][(r < 3) ? r : (r + 8)] = 0.0f;
  }
  for (int idx = tid; idx < MM * 8; idx += 384) {
    pad[idx >> 3][3 + (idx & 7)] = ssrc[idx];
  }
  if (tid < MM) {
    sA[tid]  = A[((size_t)m * NN + i) * MM + tid];
    sBW[tid] = bsrc[tid];
  }
  __syncthreads();

  // fold spline weights through the cardinal-basis matrix -> cubic coeffs
  for (int idx = tid; idx < MM * 11; idx += 384) {
    const int k = idx / 11, cm1 = idx - k * 11;   // cell-1: 0..10
    const float* bp = &pad[k][cm1];
    const float p0 = bp[0], p1 = bp[1], p2 = bp[2], p3 = bp[3];
    const float a0 = (p0 + 4.0f * p1 + p2) * (1.0f / 6.0f);
    const float a1 = (p2 - p0) * 0.5f;
    const float a2 = (p0 - 2.0f * p1 + p2) * 0.5f;
    const float a3 = (p3 - p0) * (1.0f / 6.0f) + (p1 - p2) * 0.5f;
    coef[k][cm1 + 1] = make_float4(a0, a1, a2, a3);
  }
  if (tid < MM * 2) {
    coef[tid >> 1][(tid & 1) * 12] = make_float4(0.f, 0.f, 0.f, 0.f);
  }
  __syncthreads();

  const float* BtBase = Bt + (size_t)m * MM * NN + tid;
  float acc0 = 0.0f, acc1 = 0.0f;
  for (int k = 0; k < MM; k += 2) {
    const float z0 = sA[k]     + BtBase[(size_t)k * NN];
    const float z1 = sA[k + 1] + BtBase[(size_t)(k + 1) * NN];
    {
      const float u = fmaf(z0, 2.5f, 2.5f);
      const float fu = floorf(u);
      const float t = u - fu;
      const int cc = (int)(fminf(fmaxf(fu, -4.0f), 8.0f)) + 4;
      const float4 C = coef[k][cc];
      acc0 += fmaf(t, fmaf(t, fmaf(t, C.w, C.z), C.y), C.x);
      const float sg = fastRcp(1.0f + __expf(-z0));
      acc0 = fmaf(z0 * sg, sBW[k], acc0);
    }
    {
      const float u = fmaf(z1, 2.5f, 2.5f);
      const float fu = floorf(u);
      const float t = u - fu;
      const int cc = (int)(fminf(fmaxf(fu, -4.0f), 8.0f)) + 4;
      const float4 C = coef[k + 1][cc];
      acc1 += fmaf(t, fmaf(t, fmaf(t, C.w, C.z), C.y), C.x);
      const float sg = fastRcp(1.0f + __expf(-z1));
      acc1 = fmaf(z1 * sg, sBW[k + 1], acc1);
    }
  }
  Sp[((size_t)m * NN + i) * NN + tid] = acc0 + acc1;
}

// Row kernel: weighted fuse of 3 score planes + bias, row softmax, @target,
// two final 32->32 KAN layers (relu) via float4 wave-dots. One block per row.
__global__ __launch_bounds__(384) void row_kernel(
    const float* __restrict__ Sp, const float* __restrict__ wv, const float* __restrict__ bias,
    const float* __restrict__ tg,
    const float* __restrict__ l1bw, const float* __restrict__ l1sw,
    const float* __restrict__ l2bw, const float* __restrict__ l2sw,
    float* __restrict__ out)
{
  __shared__ float p[NN];
  __shared__ float redm[6], reds[6];
  __shared__ float part[12][HH];
  __shared__ float ta[HH];
  __shared__ float basF[HH * 8];
  __shared__ float silF[HH];
  __shared__ float y1v[HH];
  const int tid = threadIdx.x;
  const int lane = tid & 63, w = tid >> 6;
  const int i = blockIdx.x;

  float stot = bias[0];
  stot = fmaf(wv[0], Sp[(size_t)i * NN + tid], stot);
  stot = fmaf(wv[1], Sp[((size_t)NN + i) * NN + tid], stot);
  stot = fmaf(wv[2], Sp[((size_t)2 * NN + i) * NN + tid], stot);

  // ---- row softmax ----
  float v = stot;
#pragma unroll
  for (int off = 32; off > 0; off >>= 1) v = fmaxf(v, __shfl_down(v, off));
  if (lane == 0) redm[w] = v;
  __syncthreads();
  float mx = redm[0];
#pragma unroll
  for (int ww = 1; ww < 6; ++ww) mx = fmaxf(mx, redm[ww]);
  const float e = __expf(stot - mx);
  p[tid] = e;
  float sv = e;
#pragma unroll
  for (int off = 32; off > 0; off >>= 1) sv += __shfl_down(sv, off);
  if (lane == 0) reds[w] = sv;
  __syncthreads();
  const float ssum = reds[0] + reds[1] + reds[2] + reds[3] + reds[4] + reds[5];
  const float inv = 1.0f / ssum;

  // ---- target_att row ----
  const int d = tid & 31, g = tid >> 5;
  float acc2 = 0.0f;
  for (int s2 = 0; s2 < 32; ++s2) {
    const int j = g * 32 + s2;
    acc2 = fmaf(p[j], tg[j * HH + d], acc2);
  }
  part[g][d] = acc2;
  if (tid < HH * 8) basF[tid] = 0.0f;
  __syncthreads();
  if (tid < HH) {
    float a = 0.0f;
#pragma unroll
    for (int gg = 0; gg < 12; ++gg) a += part[gg][tid];
    ta[tid] = a * inv;
  }
  __syncthreads();

  // ---- final KAN layer 1 (32 -> 32, relu) via float4 wave-dot ----
  if (tid < HH) {
    float b[4]; float s; int kb;
    featEval(ta[tid], s, kb, b);
    silF[tid] = s;
#pragma unroll
    for (int r = 0; r < 4; ++r) {
      const int k = kb + r;
      if ((unsigned)k < 8u) basF[tid * 8 + k] = b[r];
    }
  }
  __syncthreads();
  {
    const float4 bb = ((const float4*)basF)[lane];
    for (int o = w; o < HH; o += 6) {
      const float4* sp4 = (const float4*)(l1sw + ((size_t)o << 8));
      float acc = dot4(sp4[lane], bb);
      if (lane < HH) acc = fmaf(l1bw[o * HH + lane], silF[lane], acc);
      acc = waveReduce(acc);
      if (lane == 0) y1v[o] = fmaxf(acc, 0.0f);
    }
  }
  __syncthreads();
  if (tid < HH * 8) basF[tid] = 0.0f;
  __syncthreads();
  if (tid < HH) {
    float b[4]; float s; int kb;
    featEval(y1v[tid], s, kb, b);
    silF[tid] = s;
#pragma unroll
    for (int r = 0; r < 4; ++r) {
      const int k = kb + r;
      if ((unsigned)k < 8u) basF[tid * 8 + k] = b[r];
    }
  }
  __syncthreads();
  // ---- final KAN layer 2 (32 -> 32, relu) ----
  {
    const float4 bb = ((const float4*)basF)[lane];
    for (int o = w; o < HH; o += 6) {
      const float4* sp4 = (const float4*)(l2sw + ((size_t)o << 8));
      float acc = dot4(sp4[lane], bb);
      if (lane < HH) acc = fmaf(l2bw[o * HH + lane], silF[lane], acc);
      acc = waveReduce(acc);
      if (lane == 0) out[i * HH + o] = fmaxf(acc, 0.0f);
    }
  }
}

extern "C" void kernel_launch(void* const* d_in, const int* in_sizes, int n_in,
                              void* d_out, int out_size, void* d_ws, size_t ws_size,
                              hipStream_t stream)
{
  const float* x    = (const float*)d_in[0];
  const float* y    = (const float*)d_in[1];
  const float* tg   = (const float*)d_in[2];
  const float* bias = (const float*)d_in[3];
  const float* x1bw = (const float*)d_in[4];
  const float* x1sw = (const float*)d_in[5];
  const float* x2bw = (const float*)d_in[6];
  const float* x2sw = (const float*)d_in[7];
  const float* y1bw = (const float*)d_in[8];
  const float* y1sw = (const float*)d_in[9];
  const float* y2bw = (const float*)d_in[10];
  const float* y2sw = (const float*)d_in[11];
  const float* t1bw = (const float*)d_in[12];
  const float* t1sw = (const float*)d_in[13];
  const float* t2bw = (const float*)d_in[14];
  const float* t2sw = (const float*)d_in[15];
  const float* f1bw = (const float*)d_in[16];
  const float* f1sw = (const float*)d_in[17];
  const float* f2bw = (const float*)d_in[18];
  const float* f2sw = (const float*)d_in[19];
  const float* l1bw = (const float*)d_in[20];
  const float* l1sw = (const float*)d_in[21];
  const float* l2bw = (const float*)d_in[22];
  const float* l2sw = (const float*)d_in[23];
  float* out = (float*)d_out;

  float* ws = (float*)d_ws;
  float* A  = ws;                          // [3][384][50]
  float* Bt = ws + 3 * NN * MM;            // [3][50][384]
  float* Sp = ws + 6 * NN * MM;            // [3][384][384]
  float* wv = Sp + 3 * NN * NN;            // [3]

  stageA_kernel<<<dim3(NN + 1, 3, 2), 384, 0, stream>>>(
      x, y, tg, x1bw, x1sw, y1bw, y1sw, t1bw, t1sw,
      f1bw, f1sw, f2bw, f2sw, A, Bt, wv);
  score_kernel<<<dim3(NN, 3), 384, 0, stream>>>(A, Bt, x2bw, y2bw, t2bw,
                                                x2sw, y2sw, t2sw, Sp);
  row_kernel<<<NN, 384, 0, stream>>>(Sp, wv, bias, tg, l1bw, l1sw, l2bw, l2sw, out);
}